// Round 6
// baseline (4361.226 us; speedup 1.0000x reference)
//
#include <hip/hip_runtime.h>
#include <cstdint>
#include <cstddef>

// ---------------------------------------------------------------------------
// FlowNet3D-style encoder/decoder pyramid (GenFlow_unit_mask).
// ---------------------------------------------------------------------------

static __device__ __forceinline__ float sq3_rn(float x, float y, float z) {
    // ((x*x + y*y) + z*z) strict IEEE (no fma) to bit-match numpy
    return __fadd_rn(__fadd_rn(__fmul_rn(x, x), __fmul_rn(y, y)), __fmul_rn(z, z));
}

// monotone float -> uint map (handles negatives from catastrophic cancellation)
static __device__ __forceinline__ unsigned int ford(float f) {
    unsigned int u = __float_as_uint(f);
    return u ^ ((u >> 31) ? 0xFFFFFFFFu : 0x80000000u);
}

// ---------------------------------------------------------------------------
// Branchless DPP wave-64 u32 reductions. Result lands in lane 63.
// row_shr 1/2/4/8 accumulate within rows of 16, row_bcast15 merges row pairs,
// row_bcast31 merges halves. bound_ctrl=false -> invalid-source lanes keep
// old value (self), identity for max/min. Each step is {dpp mov, v_max/v_min}
// - no compares, no exec-mask branches.
// ---------------------------------------------------------------------------
template <int CTRL>
static __device__ __forceinline__ void dpp_umax_step(unsigned& v) {
    unsigned t = (unsigned)__builtin_amdgcn_update_dpp((int)v, (int)v, CTRL, 0xf, 0xf, false);
    v = (t > v) ? t : v;   // v_max_u32
}
template <int CTRL>
static __device__ __forceinline__ void dpp_umin_step(unsigned& v) {
    unsigned t = (unsigned)__builtin_amdgcn_update_dpp((int)v, (int)v, CTRL, 0xf, 0xf, false);
    v = (t < v) ? t : v;   // v_min_u32
}
static __device__ __forceinline__ unsigned dpp_wave_umax(unsigned v) {
    dpp_umax_step<0x111>(v);  // row_shr:1
    dpp_umax_step<0x112>(v);  // row_shr:2
    dpp_umax_step<0x114>(v);  // row_shr:4
    dpp_umax_step<0x118>(v);  // row_shr:8
    dpp_umax_step<0x142>(v);  // row_bcast:15
    dpp_umax_step<0x143>(v);  // row_bcast:31
    return v;                 // full max in lane 63
}
static __device__ __forceinline__ unsigned dpp_wave_umin(unsigned v) {
    dpp_umin_step<0x111>(v);
    dpp_umin_step<0x112>(v);
    dpp_umin_step<0x114>(v);
    dpp_umin_step<0x118>(v);
    dpp_umin_step<0x142>(v);
    dpp_umin_step<0x143>(v);
    return v;
}

// Two-phase lexicographic (hi, lo) wave argmax: max(hi), then max of lo among
// hi-matching lanes. Exact (value, tie-break) semantics, all v_max_u32.
static __device__ __forceinline__ void wave_argmax_u32pair(unsigned hi, unsigned lo,
                                                          unsigned& whi, unsigned& wlo) {
    unsigned h = dpp_wave_umax(hi);
    whi = (unsigned)__builtin_amdgcn_readlane((int)h, 63);
    unsigned cand = (hi == whi) ? lo : 0u;          // real lo > 0 always
    unsigned l = dpp_wave_umax(cand);
    wlo = (unsigned)__builtin_amdgcn_readlane((int)l, 63);
}
static __device__ __forceinline__ void wave_argmin_u32pair(unsigned hi, unsigned lo,
                                                          unsigned& whi, unsigned& wlo) {
    unsigned h = dpp_wave_umin(hi);
    whi = (unsigned)__builtin_amdgcn_readlane((int)h, 63);
    unsigned cand = (hi == whi) ? lo : 0xFFFFFFFFu; // real lo (index) < 2^31
    unsigned l = dpp_wave_umin(cand);
    wlo = (unsigned)__builtin_amdgcn_readlane((int)l, 63);
}

// ---------------------------------------------------------------------------
// FPS, multi-wave block version. One block per batch, T*P == N, P%4==0.
// LDS-STREAMED points: xyz is read from the LDS mirror every iteration
// (interleaved mapping p = j*T+t -> lane dword-stride 3, gcd(3,32)=1 ->
// exactly 2 lanes/bank = conflict-free). Only dist[P] lives in registers
// (the r5 version's 128-float register arrays exhausted the 132-VGPR
// allocation and induced hidden spill/remat VALU traffic).
// Per-thread scan uses 4 independent accumulators over quarter-ranges of j
// (breaks the P-deep dependency chain; lower quarter = smaller index, so
// strict-> merge keeps exact first-occurrence).
// Wave reduce: two-phase (hi, 0x7fffffff-bp) DPP max (exact numpy
// first-occurrence tie-break for the interleaved mapping).
// Zero global ops in the serial loop; ONE barrier/iter (parity slots).
// Dynamic LDS = N*3*4 (mirror) + M*4*4 (out). L1 = 128KB (gfx950: 160KB/CU).
// ---------------------------------------------------------------------------
template <int T, int P>
__global__ __launch_bounds__(T) __attribute__((amdgpu_waves_per_eu(1, 1)))
void fps_block(const float* __restrict__ xyz, int M,
               float* __restrict__ new_xyz, float* __restrict__ out_idx)
{
    static_assert(P % 4 == 0, "P must be a multiple of 4");
    constexpr int N = T * P;
    constexpr int NW = T / 64;
    constexpr int Q = P / 4;
    const int b = blockIdx.x;
    const int t = threadIdx.x;
    const int lane = t & 63, wave = t >> 6;

    __shared__ uint2 s_slot[2][NW];   // {hi, lo} per wave, parity-buffered
    extern __shared__ float sm[];
    float* spts = sm;           // N*3 point mirror
    float* sout = sm + N * 3;   // M*4: cx,cy,cz,(float)idx

    const float* x0 = xyz + (size_t)b * N * 3;
    for (int i = t; i < N * 3; i += T) spts[i] = x0[i];

    float dist[P];
#pragma unroll
    for (int j = 0; j < P; ++j) dist[j] = 1e10f;
    __syncthreads();

    int far = 0;
    for (int m = 0; m < M; ++m) {
        float cx = spts[far * 3 + 0];
        float cy = spts[far * 3 + 1];
        float cz = spts[far * 3 + 2];
        if (t == 0) {
            float* so = sout + m * 4;
            so[0] = cx; so[1] = cy; so[2] = cz; so[3] = (float)far;
        }
        // 4 independent quarter-scans over j (lower quarter = smaller j =
        // smaller global index; strict-> merge keeps first occurrence)
        float bv[4]; int bj[4];
#pragma unroll
        for (int a = 0; a < 4; ++a) { bv[a] = -1.0f; bj[a] = 0; }
#pragma unroll
        for (int j = 0; j < Q; ++j) {
#pragma unroll
            for (int a = 0; a < 4; ++a) {
                int jj = a * Q + j;
                int p = jj * T + t;              // interleaved mapping
                float x = spts[p * 3 + 0];
                float y = spts[p * 3 + 1];
                float z = spts[p * 3 + 2];
                float dx = __fsub_rn(x, cx);
                float dy = __fsub_rn(y, cy);
                float dz = __fsub_rn(z, cz);
                float d  = sq3_rn(dx, dy, dz);
                float nd = fminf(dist[jj], d);
                dist[jj] = nd;
                bj[a] = (nd > bv[a]) ? jj : bj[a];   // strict >: first occurrence
                bv[a] = fmaxf(bv[a], nd);
            }
        }
        float bvv = bv[0]; int bjj = bj[0];
#pragma unroll
        for (int a = 1; a < 4; ++a) {
            bjj = (bv[a] > bvv) ? bj[a] : bjj;       // tie keeps lower quarter
            bvv = fmaxf(bvv, bv[a]);
        }
        int bp = bjj * T + t;
        unsigned hi = __float_as_uint(bvv);          // bvv >= 0 -> monotone bits
        unsigned lo = 0x7fffffffu - (unsigned)bp;    // larger lo = smaller idx
        unsigned whi, wlo;
        wave_argmax_u32pair(hi, lo, whi, wlo);
        if (lane == 0) s_slot[m & 1][wave] = make_uint2(whi, wlo);
        __syncthreads();
        uint2 sv[NW];
#pragma unroll
        for (int w2 = 0; w2 < NW; ++w2) sv[w2] = s_slot[m & 1][w2];
        unsigned bhi = 0u, blo = 0u;
#pragma unroll
        for (int w2 = 0; w2 < NW; ++w2) bhi = (sv[w2].x > bhi) ? sv[w2].x : bhi;
#pragma unroll
        for (int w2 = 0; w2 < NW; ++w2) {
            unsigned c = (sv[w2].x == bhi) ? sv[w2].y : 0u;
            blo = (c > blo) ? c : blo;
        }
        far = 0x7fffffff - (int)blo;
    }

    // coalesced flush of accumulated outputs
    __syncthreads();
    for (int i = t; i < M * 3; i += T) {
        int mm = i / 3, c = i - mm * 3;
        new_xyz[(size_t)b * M * 3 + i] = sout[mm * 4 + c];
    }
    if (out_idx) {
        for (int i = t; i < M; i += T)
            out_idx[(size_t)b * M + i] = sout[i * 4 + 3];
    }
}

// ---------------------------------------------------------------------------
// FPS, single-wave version: no barriers in the loop. Thread-major mapping,
// split accumulators, single-phase DPP + ballot. Registers OK here (P<=8).
// Dynamic LDS = N*3*4 + M*4*4.
// ---------------------------------------------------------------------------
template <int P>
__global__ __launch_bounds__(64) __attribute__((amdgpu_waves_per_eu(1, 1)))
void fps_wave(const float* __restrict__ xyz, int M,
              float* __restrict__ new_xyz, float* __restrict__ out_idx)
{
    constexpr int NA = (P % 4 == 0) ? 4 : 2;
    constexpr int Q = P / NA;
    const int b = blockIdx.x;
    const int lane = threadIdx.x;
    const int N = 64 * P;
    extern __shared__ float sm[];
    float* spts = sm;           // N*3
    float* sout = sm + N * 3;   // M*4
    const float* x0 = xyz + (size_t)b * N * 3;

    for (int i = lane; i < N * 3; i += 64) spts[i] = x0[i];

    float px[P], py[P], pz[P], dist[P];
#pragma unroll
    for (int j = 0; j < P; ++j) {
        int p = lane * P + j;       // thread-major
        px[j] = x0[p * 3 + 0];
        py[j] = x0[p * 3 + 1];
        pz[j] = x0[p * 3 + 2];
        dist[j] = 1e10f;
    }
    __syncthreads();

    int far = 0;
    for (int m = 0; m < M; ++m) {
        float cx = spts[far * 3 + 0];
        float cy = spts[far * 3 + 1];
        float cz = spts[far * 3 + 2];
        if (lane == 0) {
            float* so = sout + m * 4;
            so[0] = cx; so[1] = cy; so[2] = cz; so[3] = (float)far;
        }
        float bv[NA]; int bj[NA];
#pragma unroll
        for (int a = 0; a < NA; ++a) { bv[a] = -1.0f; bj[a] = 0; }
#pragma unroll
        for (int j = 0; j < Q; ++j) {
#pragma unroll
            for (int a = 0; a < NA; ++a) {
                int idx = a * Q + j;
                float dx = __fsub_rn(px[idx], cx);
                float dy = __fsub_rn(py[idx], cy);
                float dz = __fsub_rn(pz[idx], cz);
                float d  = sq3_rn(dx, dy, dz);
                float nd = fminf(dist[idx], d);
                dist[idx] = nd;
                bj[a] = (nd > bv[a]) ? idx : bj[a];
                bv[a] = fmaxf(bv[a], nd);
            }
        }
        float bvv = bv[0]; int bjj = bj[0];
#pragma unroll
        for (int a = 1; a < NA; ++a) {
            bjj = (bv[a] > bvv) ? bj[a] : bjj;
            bvv = fmaxf(bvv, bv[a]);
        }
        unsigned hi = __float_as_uint(bvv);
        unsigned h = dpp_wave_umax(hi);
        unsigned whi = (unsigned)__builtin_amdgcn_readlane((int)h, 63);
        unsigned long long mk = __ballot(hi == whi);
        int L = (int)__builtin_ctzll(mk);
        int bjL = __builtin_amdgcn_readlane(bjj, L);
        far = L * P + bjL;
    }

    __syncthreads();
    for (int i = lane; i < M * 3; i += 64) {
        int mm = i / 3, c = i - mm * 3;
        new_xyz[(size_t)b * M * 3 + i] = sout[mm * 4 + c];
    }
    if (out_idx) {
        for (int i = lane; i < M; i += 64)
            out_idx[(size_t)b * M + i] = sout[i * 4 + 3];
    }
}

// ---------------------------------------------------------------------------
// KNN, one WAVE per query. Lane l scans candidates l, l+64, ... keeping a
// stable local sorted top-K; K rounds of branchless two-phase DPP-min on
// (ford(d), idx) reproduce lax.top_k's lexicographic-(d, idx) neighbor set.
// ---------------------------------------------------------------------------
#define KNN_QPB 4
template <int K>
__global__ void knn_wave(const float* __restrict__ query, int M,
                         const float* __restrict__ ref, int N,
                         int* __restrict__ nidx)
{
    const int b = blockIdx.y;
    const int m = blockIdx.x * KNN_QPB + threadIdx.y;
    const int lane = threadIdx.x;
    if (m >= M) return;

    const float* qp = query + ((size_t)b * M + m) * 3;
    const float qx = qp[0], qy = qp[1], qz = qp[2];
    const float sq = sq3_rn(qx, qy, qz);

    float dk[K];
    int   ik[K];
#pragma unroll
    for (int j = 0; j < K; ++j) { dk[j] = INFINITY; ik[j] = 0x7fffffff; }

    const float* rb = ref + (size_t)b * N * 3;
    for (int n = lane; n < N; n += 64) {
        const float* rp = rb + (size_t)n * 3;
        float rx = rp[0], ry = rp[1], rz = rp[2];
        float sr = sq3_rn(rx, ry, rz);
        float dot = __fadd_rn(__fadd_rn(__fmul_rn(qx, rx), __fmul_rn(qy, ry)),
                              __fmul_rn(qz, rz));
        float d = __fadd_rn(__fsub_rn(sq, __fmul_rn(2.0f, dot)), sr);
        if (d < dk[K - 1]) {
            dk[K - 1] = d;
            ik[K - 1] = n;
#pragma unroll
            for (int j = K - 1; j > 0; --j) {
                if (dk[j] < dk[j - 1]) {
                    float tv = dk[j]; dk[j] = dk[j - 1]; dk[j - 1] = tv;
                    int   ti = ik[j]; ik[j] = ik[j - 1]; ik[j - 1] = ti;
                }
            }
        }
    }

    unsigned hiA[K];
    unsigned loA[K];
#pragma unroll
    for (int j = 0; j < K; ++j) {
        hiA[j] = ford(dk[j]);
        loA[j] = (unsigned)ik[j];
    }

    int winner = 0;
    for (int r = 0; r < K; ++r) {
        unsigned bhi, blo;
        wave_argmin_u32pair(hiA[0], loA[0], bhi, blo);
        if (lane == r) winner = (int)blo;
        if (hiA[0] == bhi && loA[0] == blo) {
            // unique winner lane pops its head
#pragma unroll
            for (int j = 0; j < K - 1; ++j) { hiA[j] = hiA[j + 1]; loA[j] = loA[j + 1]; }
            hiA[K - 1] = 0xFFFFFFFFu;
            loA[K - 1] = 0xFFFFFFFFu;
        }
    }
    int* op = nidx + ((size_t)b * M + m) * K;
    if (lane < K) op[lane] = winner;
}

// ---------------------------------------------------------------------------
// SetConv: gather K neighbors, h = [nbr_xyz - center, nbr_feat],
// 2-layer MLP + ReLU, max-pool over K. One wave per query.
// ---------------------------------------------------------------------------
template <int K>
__global__ void setconv_kernel(const float* __restrict__ ref_xyz, int N,
                               const float* __restrict__ ref_feat, int Cin,
                               const float* __restrict__ new_xyz, int M,
                               const int* __restrict__ nidx,
                               const float* __restrict__ W0, const float* __restrict__ b0, int C1,
                               const float* __restrict__ W1, const float* __restrict__ b1, int C2,
                               float* __restrict__ out)
{
    const int b = blockIdx.y, q = blockIdx.x;
    const int lane = threadIdx.x;
    const int Cin3 = Cin + 3;
    extern __shared__ float sm[];
    float* h  = sm;              // K * Cin3
    float* h1 = sm + K * Cin3;   // K * C1

    const size_t qg = (size_t)b * M + q;
    const float cx = new_xyz[qg * 3 + 0];
    const float cy = new_xyz[qg * 3 + 1];
    const float cz = new_xyz[qg * 3 + 2];

    for (int j = 0; j < K; ++j) {
        int n = nidx[qg * K + j];
        const float* xp = ref_xyz + ((size_t)b * N + n) * 3;
        const float* fp = ref_feat + ((size_t)b * N + n) * Cin;
        for (int i = lane; i < Cin3; i += 64) {
            float v;
            if (i == 0)      v = __fsub_rn(xp[0], cx);
            else if (i == 1) v = __fsub_rn(xp[1], cy);
            else if (i == 2) v = __fsub_rn(xp[2], cz);
            else             v = fp[i - 3];
            h[j * Cin3 + i] = v;
        }
    }
    __syncthreads();

    for (int c0 = 0; c0 < C1; c0 += 64) {
        int c = c0 + lane;
        bool act = c < C1;
        float acc[K];
        float bias = act ? b0[c] : 0.0f;
#pragma unroll
        for (int j = 0; j < K; ++j) acc[j] = bias;
        for (int i = 0; i < Cin3; ++i) {
            float w = act ? W0[(size_t)i * C1 + c] : 0.0f;
#pragma unroll
            for (int j = 0; j < K; ++j) acc[j] = fmaf(h[j * Cin3 + i], w, acc[j]);
        }
        if (act) {
#pragma unroll
            for (int j = 0; j < K; ++j) h1[j * C1 + c] = fmaxf(acc[j], 0.0f);
        }
    }
    __syncthreads();

    for (int c0 = 0; c0 < C2; c0 += 64) {
        int c = c0 + lane;
        bool act = c < C2;
        float acc[K];
        float bias = act ? b1[c] : 0.0f;
#pragma unroll
        for (int j = 0; j < K; ++j) acc[j] = bias;
        for (int i = 0; i < C1; ++i) {
            float w = act ? W1[(size_t)i * C2 + c] : 0.0f;
#pragma unroll
            for (int j = 0; j < K; ++j) acc[j] = fmaf(h1[j * C1 + i], w, acc[j]);
        }
        if (act) {
            float mv = acc[0];
#pragma unroll
            for (int j = 1; j < K; ++j) mv = fmaxf(mv, acc[j]);
            out[qg * C2 + c] = fmaxf(mv, 0.0f);
        }
    }
}

// ---------------------------------------------------------------------------
// SetUpConv: h=[cx-fx, cf]; MLP1+pool; concat with ff; MLP2. One wave/query.
// ---------------------------------------------------------------------------
template <int K>
__global__ void setupconv_kernel(const float* __restrict__ cxyz, int Nc,
                                 const float* __restrict__ cf, int Cc,
                                 const float* __restrict__ fxyz, int M,
                                 const float* __restrict__ ff, int Cf,
                                 const int* __restrict__ nidx,
                                 const float* __restrict__ W1, const float* __restrict__ b1, int C1,
                                 const float* __restrict__ W2, const float* __restrict__ b2, int C2,
                                 float* __restrict__ out)
{
    const int b = blockIdx.y, q = blockIdx.x;
    const int lane = threadIdx.x;
    const int Cc3 = Cc + 3;
    extern __shared__ float sm[];
    float* h = sm;            // K * Cc3
    float* g = sm + K * Cc3;  // C1 + Cf

    const size_t qg = (size_t)b * M + q;
    const float px = fxyz[qg * 3 + 0];
    const float py = fxyz[qg * 3 + 1];
    const float pz = fxyz[qg * 3 + 2];

    for (int j = 0; j < K; ++j) {
        int n = nidx[qg * K + j];
        const float* xp = cxyz + ((size_t)b * Nc + n) * 3;
        const float* fp = cf + ((size_t)b * Nc + n) * Cc;
        for (int i = lane; i < Cc3; i += 64) {
            float v;
            if (i == 0)      v = __fsub_rn(xp[0], px);
            else if (i == 1) v = __fsub_rn(xp[1], py);
            else if (i == 2) v = __fsub_rn(xp[2], pz);
            else             v = fp[i - 3];
            h[j * Cc3 + i] = v;
        }
    }
    for (int i = lane; i < Cf; i += 64) g[C1 + i] = ff[qg * Cf + i];
    __syncthreads();

    for (int c0 = 0; c0 < C1; c0 += 64) {
        int c = c0 + lane;
        bool act = c < C1;
        float acc[K];
        float bias = act ? b1[c] : 0.0f;
#pragma unroll
        for (int j = 0; j < K; ++j) acc[j] = bias;
        for (int i = 0; i < Cc3; ++i) {
            float w = act ? W1[(size_t)i * C1 + c] : 0.0f;
#pragma unroll
            for (int j = 0; j < K; ++j) acc[j] = fmaf(h[j * Cc3 + i], w, acc[j]);
        }
        if (act) {
            float mv = acc[0];
#pragma unroll
            for (int j = 1; j < K; ++j) mv = fmaxf(mv, acc[j]);
            g[c] = fmaxf(mv, 0.0f);
        }
    }
    __syncthreads();

    const int Cg = C1 + Cf;
    for (int c0 = 0; c0 < C2; c0 += 64) {
        int c = c0 + lane;
        bool act = c < C2;
        float acc = act ? b2[c] : 0.0f;
        for (int i = 0; i < Cg; ++i) {
            float w = act ? W2[(size_t)i * C2 + c] : 0.0f;
            acc = fmaf(g[i], w, acc);
        }
        if (act) out[qg * C2 + c] = fmaxf(acc, 0.0f);
    }
}

// ---------------------------------------------------------------------------
// f0 = relu(feat @ d0_W + d0_b), 3 -> 32 channels.
// ---------------------------------------------------------------------------
__global__ void f0_kernel(const float* __restrict__ feat, const float* __restrict__ W,
                          const float* __restrict__ bias, float* __restrict__ out)
{
    int t = blockIdx.x * blockDim.x + threadIdx.x;
    int n = t >> 5, c = t & 31;
    const float* f = feat + (size_t)n * 3;
    float acc = bias[c];
    acc = fmaf(f[0], W[c], acc);
    acc = fmaf(f[1], W[32 + c], acc);
    acc = fmaf(f[2], W[64 + c], acc);
    out[t] = fmaxf(acc, 0.0f);
}

// ---------------------------------------------------------------------------

extern "C" void kernel_launch(void* const* d_in, const int* in_sizes, int n_in,
                              void* d_out, int out_size, void* d_ws, size_t ws_size,
                              hipStream_t stream)
{
    const float* pc    = (const float*)d_in[0];
    const float* feat  = (const float*)d_in[1];
    const float* d0_W  = (const float*)d_in[2];
    const float* d0_b  = (const float*)d_in[3];
    const float* d1_W0 = (const float*)d_in[4];
    const float* d1_b0 = (const float*)d_in[5];
    const float* d1_W1 = (const float*)d_in[6];
    const float* d1_b1 = (const float*)d_in[7];
    const float* d2_W0 = (const float*)d_in[8];
    const float* d2_b0 = (const float*)d_in[9];
    const float* d2_W1 = (const float*)d_in[10];
    const float* d2_b1 = (const float*)d_in[11];
    const float* d3_W0 = (const float*)d_in[12];
    const float* d3_b0 = (const float*)d_in[13];
    const float* d3_W1 = (const float*)d_in[14];
    const float* d3_b1 = (const float*)d_in[15];
    const float* d4_W0 = (const float*)d_in[16];
    const float* d4_b0 = (const float*)d_in[17];
    const float* d4_W1 = (const float*)d_in[18];
    const float* d4_b1 = (const float*)d_in[19];
    const float* u4_W1 = (const float*)d_in[20];
    const float* u4_b1 = (const float*)d_in[21];
    const float* u4_W2 = (const float*)d_in[22];
    const float* u4_b2 = (const float*)d_in[23];
    const float* u3_W1 = (const float*)d_in[24];
    const float* u3_b1 = (const float*)d_in[25];
    const float* u3_W2 = (const float*)d_in[26];
    const float* u3_b2 = (const float*)d_in[27];
    const float* u2_W1 = (const float*)d_in[28];
    const float* u2_b1 = (const float*)d_in[29];
    const float* u2_W2 = (const float*)d_in[30];
    const float* u2_b2 = (const float*)d_in[31];
    const float* u1_W1 = (const float*)d_in[32];
    const float* u1_b1 = (const float*)d_in[33];
    const float* u1_W2 = (const float*)d_in[34];
    const float* u1_b2 = (const float*)d_in[35];

    float* out = (float*)d_out;
    float* o_x1 = out + 0;       // 12288
    float* o_x2 = out + 12288;   // 3072
    float* o_x3 = out + 15360;   // 768
    float* o_i1 = out + 16128;   // 4096
    float* o_i2 = out + 20224;   // 1024
    float* o_i3 = out + 21248;   // 256
    float* o_u0 = out + 21504;   // 524288
    float* o_u1 = out + 545792;  // 262144
    float* o_u2 = out + 807936;  // 131072
    float* o_u3 = out + 939008;  // 49152

    float* w = (float*)d_ws;
    float* f0 = w; w += 2 * 8192 * 32;
    float* f1 = w; w += 2 * 2048 * 64;
    float* f2 = w; w += 2 * 512 * 128;
    float* f3 = w; w += 2 * 128 * 192;
    float* f4 = w; w += 2 * 64 * 192;
    float* x4 = w; w += 2 * 64 * 3;
    int* nidx = (int*)w;         // up to 2*8192*8 ints

    const int B = 2;
    const dim3 kb(64, KNN_QPB);

    // raise dynamic-LDS cap for the 128KB level-1 FPS (idempotent; gfx950 has
    // 160KB/CU). Not a stream op -> legal under graph capture.
    static bool attr_done = false;
    if (!attr_done) {
        (void)hipFuncSetAttribute((const void*)fps_block<256, 32>,
                                  hipFuncAttributeMaxDynamicSharedMemorySize,
                                  8192 * 3 * 4 + 2048 * 4 * 4);
        attr_done = true;
    }

    // f0
    f0_kernel<<<(2 * 8192 * 32) / 256, 256, 0, stream>>>(feat, d0_W, d0_b, f0);

    // ---- level 1: 8192 -> 2048, k=16, Cin=32, MLP 35->32->64
    fps_block<256, 32><<<B, 256, 8192 * 3 * 4 + 2048 * 4 * 4, stream>>>(pc, 2048, o_x1, o_i1);
    knn_wave<16><<<dim3(2048 / KNN_QPB, B), kb, 0, stream>>>(o_x1, 2048, pc, 8192, nidx);
    setconv_kernel<16><<<dim3(2048, B), 64, (16 * 35 + 16 * 32) * 4, stream>>>(
        pc, 8192, f0, 32, o_x1, 2048, nidx, d1_W0, d1_b0, 32, d1_W1, d1_b1, 64, f1);

    // ---- level 2: 2048 -> 512, Cin=64, MLP 67->64->128
    fps_block<256, 8><<<B, 256, 2048 * 3 * 4 + 512 * 4 * 4, stream>>>(o_x1, 512, o_x2, o_i2);
    knn_wave<16><<<dim3(512 / KNN_QPB, B), kb, 0, stream>>>(o_x2, 512, o_x1, 2048, nidx);
    setconv_kernel<16><<<dim3(512, B), 64, (16 * 67 + 16 * 64) * 4, stream>>>(
        o_x1, 2048, f1, 64, o_x2, 512, nidx, d2_W0, d2_b0, 64, d2_W1, d2_b1, 128, f2);

    // ---- level 3: 512 -> 128, Cin=128, MLP 131->128->192
    fps_wave<8><<<B, 64, 512 * 3 * 4 + 128 * 4 * 4, stream>>>(o_x2, 128, o_x3, o_i3);
    knn_wave<16><<<dim3(128 / KNN_QPB, B), kb, 0, stream>>>(o_x3, 128, o_x2, 512, nidx);
    setconv_kernel<16><<<dim3(128, B), 64, (16 * 131 + 16 * 128) * 4, stream>>>(
        o_x2, 512, f2, 128, o_x3, 128, nidx, d3_W0, d3_b0, 128, d3_W1, d3_b1, 192, f3);

    // ---- level 4: 128 -> 64, Cin=192, MLP 195->192->192
    fps_wave<2><<<B, 64, 128 * 3 * 4 + 64 * 4 * 4, stream>>>(o_x3, 64, x4, nullptr);
    knn_wave<16><<<dim3(64 / KNN_QPB, B), kb, 0, stream>>>(x4, 64, o_x3, 128, nidx);
    setconv_kernel<16><<<dim3(64, B), 64, (16 * 195 + 16 * 192) * 4, stream>>>(
        o_x3, 128, f3, 192, x4, 64, nidx, d4_W0, d4_b0, 192, d4_W1, d4_b1, 192, f4);

    // ---- u3: fine=x3(128), coarse=x4(64), cf=f4(192), ff=f3(192)
    knn_wave<8><<<dim3(128 / KNN_QPB, B), kb, 0, stream>>>(o_x3, 128, x4, 64, nidx);
    setupconv_kernel<8><<<dim3(128, B), 64, (8 * 195 + 192 + 192) * 4, stream>>>(
        x4, 64, f4, 192, o_x3, 128, f3, 192, nidx,
        u4_W1, u4_b1, 192, u4_W2, u4_b2, 192, o_u3);

    // ---- u2: fine=x2(512), coarse=x3(128), cf=u3(192), ff=f2(128)
    knn_wave<8><<<dim3(512 / KNN_QPB, B), kb, 0, stream>>>(o_x2, 512, o_x3, 128, nidx);
    setupconv_kernel<8><<<dim3(512, B), 64, (8 * 195 + 128 + 128) * 4, stream>>>(
        o_x3, 128, o_u3, 192, o_x2, 512, f2, 128, nidx,
        u3_W1, u3_b1, 128, u3_W2, u3_b2, 128, o_u2);

    // ---- u1: fine=x1(2048), coarse=x2(512), cf=u2(128), ff=f1(64)
    knn_wave<8><<<dim3(2048 / KNN_QPB, B), kb, 0, stream>>>(o_x1, 2048, o_x2, 512, nidx);
    setupconv_kernel<8><<<dim3(2048, B), 64, (8 * 131 + 64 + 64) * 4, stream>>>(
        o_x2, 512, o_u2, 128, o_x1, 2048, f1, 64, nidx,
        u2_W1, u2_b1, 64, u2_W2, u2_b2, 64, o_u1);

    // ---- u0: fine=pc(8192), coarse=x1(2048), cf=u1(64), ff=f0(32)
    knn_wave<8><<<dim3(8192 / KNN_QPB, B), kb, 0, stream>>>(pc, 8192, o_x1, 2048, nidx);
    setupconv_kernel<8><<<dim3(8192, B), 64, (8 * 67 + 32 + 32) * 4, stream>>>(
        o_x1, 2048, o_u1, 64, pc, 8192, f0, 32, nidx,
        u1_W1, u1_b1, 32, u1_W2, u1_b2, 32, o_u0);
}

// Round 7
// 3555.717 us; speedup vs baseline: 1.2265x; 1.2265x over previous
//
#include <hip/hip_runtime.h>
#include <cstdint>
#include <cstddef>

// ---------------------------------------------------------------------------
// FlowNet3D-style encoder/decoder pyramid (GenFlow_unit_mask).
// ---------------------------------------------------------------------------

static __device__ __forceinline__ float sq3_rn(float x, float y, float z) {
    // ((x*x + y*y) + z*z) strict IEEE (no fma) to bit-match numpy
    return __fadd_rn(__fadd_rn(__fmul_rn(x, x), __fmul_rn(y, y)), __fmul_rn(z, z));
}

// monotone float -> uint map (handles negatives from catastrophic cancellation)
static __device__ __forceinline__ unsigned int ford(float f) {
    unsigned int u = __float_as_uint(f);
    return u ^ ((u >> 31) ? 0xFFFFFFFFu : 0x80000000u);
}

// ---------------------------------------------------------------------------
// f64-packed lexicographic wave argmax.
// key = double with high word = float bits of the (non-negative) best value
// and low word = 0x7fffffff - point_index. hi <= bits(1e10) = 0x501502F9 so
// the double's exponent field is never all-ones -> never NaN/Inf, always
// positive -> NUMERIC double order == LEXICOGRAPHIC (hi, lo) u64 order.
// One v_max_f64 per DPP step (vs cmp+cndmask pairs), no mid-chain readlane.
// Result lands in lane 63. bound_ctrl=false -> invalid lanes keep self
// (identity for max).
// ---------------------------------------------------------------------------
template <int CTRL>
static __device__ __forceinline__ double dpp_fmax64_step(double v) {
    int lo = __double2loint(v), hi = __double2hiint(v);
    int lo2 = __builtin_amdgcn_update_dpp(lo, lo, CTRL, 0xf, 0xf, false);
    int hi2 = __builtin_amdgcn_update_dpp(hi, hi, CTRL, 0xf, 0xf, false);
    return fmax(v, __hiloint2double(hi2, lo2));
}
static __device__ __forceinline__ double dpp_wave_fmax64(double v) {
    v = dpp_fmax64_step<0x111>(v);  // row_shr:1
    v = dpp_fmax64_step<0x112>(v);  // row_shr:2
    v = dpp_fmax64_step<0x114>(v);  // row_shr:4
    v = dpp_fmax64_step<0x118>(v);  // row_shr:8
    v = dpp_fmax64_step<0x142>(v);  // row_bcast:15
    v = dpp_fmax64_step<0x143>(v);  // row_bcast:31
    return v;                       // full max in lane 63
}

// ---------------------------------------------------------------------------
// Branchless DPP wave-64 u32 min reductions (for KNN; values there can make
// the f64 packing NaN, so KNN keeps the proven two-phase u32 form).
// ---------------------------------------------------------------------------
template <int CTRL>
static __device__ __forceinline__ void dpp_umin_step(unsigned& v) {
    unsigned t = (unsigned)__builtin_amdgcn_update_dpp((int)v, (int)v, CTRL, 0xf, 0xf, false);
    v = (t < v) ? t : v;   // v_min_u32
}
static __device__ __forceinline__ unsigned dpp_wave_umin(unsigned v) {
    dpp_umin_step<0x111>(v);
    dpp_umin_step<0x112>(v);
    dpp_umin_step<0x114>(v);
    dpp_umin_step<0x118>(v);
    dpp_umin_step<0x142>(v);
    dpp_umin_step<0x143>(v);
    return v;
}
static __device__ __forceinline__ void wave_argmin_u32pair(unsigned hi, unsigned lo,
                                                          unsigned& whi, unsigned& wlo) {
    unsigned h = dpp_wave_umin(hi);
    whi = (unsigned)__builtin_amdgcn_readlane((int)h, 63);
    unsigned cand = (hi == whi) ? lo : 0xFFFFFFFFu; // real lo (index) < 2^31
    unsigned l = dpp_wave_umin(cand);
    wlo = (unsigned)__builtin_amdgcn_readlane((int)l, 63);
}

// ---------------------------------------------------------------------------
// FPS, multi-wave block version. One block per batch, T*P == N, P%4==0.
// Interleaved mapping p = j*T + t. HYBRID residency: xyz of the first RREG
// point-slots lives in registers; the rest stream from the LDS mirror
// (dword-stride 3 -> 2 lanes/bank = conflict-free). dist[] all in registers.
// This keeps the total register footprint ~125 (vs 128 xyz+dist floats that
// overflowed the 132-VGPR allocation into AGPRs -> hidden accvgpr mov tax).
// Per-thread scan: 4 independent accumulators over quarter-ranges of j
// (breaks the P-deep dependency chain; ascending merge keeps exact
// first-occurrence). Wave reduce + cross-wave merge: f64-packed single phase.
// Zero global ops in the serial loop; ONE barrier/iter (parity slots).
// Dynamic LDS = N*3*4 (mirror) + M*4*4 (out). L1 = 128KB (gfx950: 160KB/CU).
// ---------------------------------------------------------------------------
template <int T, int P>
__global__ __launch_bounds__(T) __attribute__((amdgpu_waves_per_eu(1, 1)))
void fps_block(const float* __restrict__ xyz, int M,
               float* __restrict__ new_xyz, float* __restrict__ out_idx)
{
    static_assert(P % 4 == 0, "P must be a multiple of 4");
    constexpr int N = T * P;
    constexpr int NW = T / 64;
    constexpr int Q = P / 4;
    constexpr int RREG = (P > 22) ? 22 : P;   // register-resident point slots
    const int b = blockIdx.x;
    const int t = threadIdx.x;
    const int lane = t & 63, wave = t >> 6;

    __shared__ double s_slot[2][NW];  // packed (hi,lo) keys, parity-buffered
    extern __shared__ float sm[];
    float* spts = sm;           // N*3 point mirror
    float* sout = sm + N * 3;   // M*4: cx,cy,cz,(float)idx

    const float* x0 = xyz + (size_t)b * N * 3;
    for (int i = t; i < N * 3; i += T) spts[i] = x0[i];

    float px[RREG], py[RREG], pz[RREG], dist[P];
#pragma unroll
    for (int j = 0; j < RREG; ++j) {
        int p = j * T + t;
        px[j] = x0[p * 3 + 0];
        py[j] = x0[p * 3 + 1];
        pz[j] = x0[p * 3 + 2];
    }
#pragma unroll
    for (int j = 0; j < P; ++j) dist[j] = 1e10f;
    __syncthreads();

    int far = 0;
    for (int m = 0; m < M; ++m) {
        float cx = spts[far * 3 + 0];
        float cy = spts[far * 3 + 1];
        float cz = spts[far * 3 + 2];
        if (t == 0) {
            float* so = sout + m * 4;
            so[0] = cx; so[1] = cy; so[2] = cz; so[3] = (float)far;
        }
        // 4 independent quarter-scans over j (lower quarter = smaller j =
        // smaller global index; strict-> merge keeps first occurrence)
        float bv[4]; int bj[4];
#pragma unroll
        for (int a = 0; a < 4; ++a) { bv[a] = -1.0f; bj[a] = 0; }
#pragma unroll
        for (int j = 0; j < Q; ++j) {
#pragma unroll
            for (int a = 0; a < 4; ++a) {
                const int jj = a * Q + j;
                float x, y, z;
                if (jj < RREG) {            // compile-time fold (unrolled)
                    x = px[jj]; y = py[jj]; z = pz[jj];
                } else {
                    int p3 = (jj * T + t) * 3;
                    x = spts[p3 + 0]; y = spts[p3 + 1]; z = spts[p3 + 2];
                }
                float dx = __fsub_rn(x, cx);
                float dy = __fsub_rn(y, cy);
                float dz = __fsub_rn(z, cz);
                float d  = sq3_rn(dx, dy, dz);
                float nd = fminf(dist[jj], d);
                dist[jj] = nd;
                bj[a] = (nd > bv[a]) ? jj : bj[a];   // strict >: first occurrence
                bv[a] = fmaxf(bv[a], nd);
            }
        }
        float bvv = bv[0]; int bjj = bj[0];
#pragma unroll
        for (int a = 1; a < 4; ++a) {
            bjj = (bv[a] > bvv) ? bj[a] : bjj;       // tie keeps lower quarter
            bvv = fmaxf(bvv, bv[a]);
        }
        int bp = bjj * T + t;
        unsigned hi = __float_as_uint(bvv);          // bvv >= 0 -> monotone bits
        unsigned lo = 0x7fffffffu - (unsigned)bp;    // larger lo = smaller idx
        double key = __hiloint2double((int)hi, (int)lo);
        key = dpp_wave_fmax64(key);
        if (lane == 63) s_slot[m & 1][wave] = key;
        __syncthreads();
        double best = s_slot[m & 1][0];
#pragma unroll
        for (int w2 = 1; w2 < NW; ++w2) best = fmax(best, s_slot[m & 1][w2]);
        far = 0x7fffffff - __double2loint(best);
    }

    // coalesced flush of accumulated outputs
    __syncthreads();
    for (int i = t; i < M * 3; i += T) {
        int mm = i / 3, c = i - mm * 3;
        new_xyz[(size_t)b * M * 3 + i] = sout[mm * 4 + c];
    }
    if (out_idx) {
        for (int i = t; i < M; i += T)
            out_idx[(size_t)b * M + i] = sout[i * 4 + 3];
    }
}

// ---------------------------------------------------------------------------
// FPS, single-wave version: no barriers in the loop. Thread-major mapping,
// split accumulators, f64-packed single-phase reduce (result broadcast via
// readlane from lane 63). Registers fine here (P<=8).
// Dynamic LDS = N*3*4 + M*4*4.
// ---------------------------------------------------------------------------
template <int P>
__global__ __launch_bounds__(64) __attribute__((amdgpu_waves_per_eu(1, 1)))
void fps_wave(const float* __restrict__ xyz, int M,
              float* __restrict__ new_xyz, float* __restrict__ out_idx)
{
    constexpr int NA = (P % 4 == 0) ? 4 : 2;
    constexpr int Q = P / NA;
    const int b = blockIdx.x;
    const int lane = threadIdx.x;
    const int N = 64 * P;
    extern __shared__ float sm[];
    float* spts = sm;           // N*3
    float* sout = sm + N * 3;   // M*4
    const float* x0 = xyz + (size_t)b * N * 3;

    for (int i = lane; i < N * 3; i += 64) spts[i] = x0[i];

    float px[P], py[P], pz[P], dist[P];
#pragma unroll
    for (int j = 0; j < P; ++j) {
        int p = lane * P + j;       // thread-major
        px[j] = x0[p * 3 + 0];
        py[j] = x0[p * 3 + 1];
        pz[j] = x0[p * 3 + 2];
        dist[j] = 1e10f;
    }
    __syncthreads();

    int far = 0;
    for (int m = 0; m < M; ++m) {
        float cx = spts[far * 3 + 0];
        float cy = spts[far * 3 + 1];
        float cz = spts[far * 3 + 2];
        if (lane == 0) {
            float* so = sout + m * 4;
            so[0] = cx; so[1] = cy; so[2] = cz; so[3] = (float)far;
        }
        float bv[NA]; int bj[NA];
#pragma unroll
        for (int a = 0; a < NA; ++a) { bv[a] = -1.0f; bj[a] = 0; }
#pragma unroll
        for (int j = 0; j < Q; ++j) {
#pragma unroll
            for (int a = 0; a < NA; ++a) {
                int idx = a * Q + j;
                float dx = __fsub_rn(px[idx], cx);
                float dy = __fsub_rn(py[idx], cy);
                float dz = __fsub_rn(pz[idx], cz);
                float d  = sq3_rn(dx, dy, dz);
                float nd = fminf(dist[idx], d);
                dist[idx] = nd;
                bj[a] = (nd > bv[a]) ? idx : bj[a];
                bv[a] = fmaxf(bv[a], nd);
            }
        }
        float bvv = bv[0]; int bjj = bj[0];
#pragma unroll
        for (int a = 1; a < NA; ++a) {
            bjj = (bv[a] > bvv) ? bj[a] : bjj;
            bvv = fmaxf(bvv, bv[a]);
        }
        int bp = lane * P + bjj;
        unsigned hi = __float_as_uint(bvv);
        unsigned lo = 0x7fffffffu - (unsigned)bp;
        double key = __hiloint2double((int)hi, (int)lo);
        key = dpp_wave_fmax64(key);
        int wlo = __builtin_amdgcn_readlane(__double2loint(key), 63);
        far = 0x7fffffff - wlo;
    }

    __syncthreads();
    for (int i = lane; i < M * 3; i += 64) {
        int mm = i / 3, c = i - mm * 3;
        new_xyz[(size_t)b * M * 3 + i] = sout[mm * 4 + c];
    }
    if (out_idx) {
        for (int i = lane; i < M; i += 64)
            out_idx[(size_t)b * M + i] = sout[i * 4 + 3];
    }
}

// ---------------------------------------------------------------------------
// KNN, one WAVE per query. Lane l scans candidates l, l+64, ... keeping a
// stable local sorted top-K; K rounds of branchless two-phase DPP-min on
// (ford(d), idx) reproduce lax.top_k's lexicographic-(d, idx) neighbor set.
// ---------------------------------------------------------------------------
#define KNN_QPB 4
template <int K>
__global__ void knn_wave(const float* __restrict__ query, int M,
                         const float* __restrict__ ref, int N,
                         int* __restrict__ nidx)
{
    const int b = blockIdx.y;
    const int m = blockIdx.x * KNN_QPB + threadIdx.y;
    const int lane = threadIdx.x;
    if (m >= M) return;

    const float* qp = query + ((size_t)b * M + m) * 3;
    const float qx = qp[0], qy = qp[1], qz = qp[2];
    const float sq = sq3_rn(qx, qy, qz);

    float dk[K];
    int   ik[K];
#pragma unroll
    for (int j = 0; j < K; ++j) { dk[j] = INFINITY; ik[j] = 0x7fffffff; }

    const float* rb = ref + (size_t)b * N * 3;
    for (int n = lane; n < N; n += 64) {
        const float* rp = rb + (size_t)n * 3;
        float rx = rp[0], ry = rp[1], rz = rp[2];
        float sr = sq3_rn(rx, ry, rz);
        float dot = __fadd_rn(__fadd_rn(__fmul_rn(qx, rx), __fmul_rn(qy, ry)),
                              __fmul_rn(qz, rz));
        float d = __fadd_rn(__fsub_rn(sq, __fmul_rn(2.0f, dot)), sr);
        if (d < dk[K - 1]) {
            dk[K - 1] = d;
            ik[K - 1] = n;
#pragma unroll
            for (int j = K - 1; j > 0; --j) {
                if (dk[j] < dk[j - 1]) {
                    float tv = dk[j]; dk[j] = dk[j - 1]; dk[j - 1] = tv;
                    int   ti = ik[j]; ik[j] = ik[j - 1]; ik[j - 1] = ti;
                }
            }
        }
    }

    unsigned hiA[K];
    unsigned loA[K];
#pragma unroll
    for (int j = 0; j < K; ++j) {
        hiA[j] = ford(dk[j]);
        loA[j] = (unsigned)ik[j];
    }

    int winner = 0;
    for (int r = 0; r < K; ++r) {
        unsigned bhi, blo;
        wave_argmin_u32pair(hiA[0], loA[0], bhi, blo);
        if (lane == r) winner = (int)blo;
        if (hiA[0] == bhi && loA[0] == blo) {
            // unique winner lane pops its head
#pragma unroll
            for (int j = 0; j < K - 1; ++j) { hiA[j] = hiA[j + 1]; loA[j] = loA[j + 1]; }
            hiA[K - 1] = 0xFFFFFFFFu;
            loA[K - 1] = 0xFFFFFFFFu;
        }
    }
    int* op = nidx + ((size_t)b * M + m) * K;
    if (lane < K) op[lane] = winner;
}

// ---------------------------------------------------------------------------
// SetConv: gather K neighbors, h = [nbr_xyz - center, nbr_feat],
// 2-layer MLP + ReLU, max-pool over K. One wave per query.
// ---------------------------------------------------------------------------
template <int K>
__global__ void setconv_kernel(const float* __restrict__ ref_xyz, int N,
                               const float* __restrict__ ref_feat, int Cin,
                               const float* __restrict__ new_xyz, int M,
                               const int* __restrict__ nidx,
                               const float* __restrict__ W0, const float* __restrict__ b0, int C1,
                               const float* __restrict__ W1, const float* __restrict__ b1, int C2,
                               float* __restrict__ out)
{
    const int b = blockIdx.y, q = blockIdx.x;
    const int lane = threadIdx.x;
    const int Cin3 = Cin + 3;
    extern __shared__ float sm[];
    float* h  = sm;              // K * Cin3
    float* h1 = sm + K * Cin3;   // K * C1

    const size_t qg = (size_t)b * M + q;
    const float cx = new_xyz[qg * 3 + 0];
    const float cy = new_xyz[qg * 3 + 1];
    const float cz = new_xyz[qg * 3 + 2];

    for (int j = 0; j < K; ++j) {
        int n = nidx[qg * K + j];
        const float* xp = ref_xyz + ((size_t)b * N + n) * 3;
        const float* fp = ref_feat + ((size_t)b * N + n) * Cin;
        for (int i = lane; i < Cin3; i += 64) {
            float v;
            if (i == 0)      v = __fsub_rn(xp[0], cx);
            else if (i == 1) v = __fsub_rn(xp[1], cy);
            else if (i == 2) v = __fsub_rn(xp[2], cz);
            else             v = fp[i - 3];
            h[j * Cin3 + i] = v;
        }
    }
    __syncthreads();

    for (int c0 = 0; c0 < C1; c0 += 64) {
        int c = c0 + lane;
        bool act = c < C1;
        float acc[K];
        float bias = act ? b0[c] : 0.0f;
#pragma unroll
        for (int j = 0; j < K; ++j) acc[j] = bias;
        for (int i = 0; i < Cin3; ++i) {
            float w = act ? W0[(size_t)i * C1 + c] : 0.0f;
#pragma unroll
            for (int j = 0; j < K; ++j) acc[j] = fmaf(h[j * Cin3 + i], w, acc[j]);
        }
        if (act) {
#pragma unroll
            for (int j = 0; j < K; ++j) h1[j * C1 + c] = fmaxf(acc[j], 0.0f);
        }
    }
    __syncthreads();

    for (int c0 = 0; c0 < C2; c0 += 64) {
        int c = c0 + lane;
        bool act = c < C2;
        float acc[K];
        float bias = act ? b1[c] : 0.0f;
#pragma unroll
        for (int j = 0; j < K; ++j) acc[j] = bias;
        for (int i = 0; i < C1; ++i) {
            float w = act ? W1[(size_t)i * C2 + c] : 0.0f;
#pragma unroll
            for (int j = 0; j < K; ++j) acc[j] = fmaf(h1[j * C1 + i], w, acc[j]);
        }
        if (act) {
            float mv = acc[0];
#pragma unroll
            for (int j = 1; j < K; ++j) mv = fmaxf(mv, acc[j]);
            out[qg * C2 + c] = fmaxf(mv, 0.0f);
        }
    }
}

// ---------------------------------------------------------------------------
// SetUpConv: h=[cx-fx, cf]; MLP1+pool; concat with ff; MLP2. One wave/query.
// ---------------------------------------------------------------------------
template <int K>
__global__ void setupconv_kernel(const float* __restrict__ cxyz, int Nc,
                                 const float* __restrict__ cf, int Cc,
                                 const float* __restrict__ fxyz, int M,
                                 const float* __restrict__ ff, int Cf,
                                 const int* __restrict__ nidx,
                                 const float* __restrict__ W1, const float* __restrict__ b1, int C1,
                                 const float* __restrict__ W2, const float* __restrict__ b2, int C2,
                                 float* __restrict__ out)
{
    const int b = blockIdx.y, q = blockIdx.x;
    const int lane = threadIdx.x;
    const int Cc3 = Cc + 3;
    extern __shared__ float sm[];
    float* h = sm;            // K * Cc3
    float* g = sm + K * Cc3;  // C1 + Cf

    const size_t qg = (size_t)b * M + q;
    const float px = fxyz[qg * 3 + 0];
    const float py = fxyz[qg * 3 + 1];
    const float pz = fxyz[qg * 3 + 2];

    for (int j = 0; j < K; ++j) {
        int n = nidx[qg * K + j];
        const float* xp = cxyz + ((size_t)b * Nc + n) * 3;
        const float* fp = cf + ((size_t)b * Nc + n) * Cc;
        for (int i = lane; i < Cc3; i += 64) {
            float v;
            if (i == 0)      v = __fsub_rn(xp[0], px);
            else if (i == 1) v = __fsub_rn(xp[1], py);
            else if (i == 2) v = __fsub_rn(xp[2], pz);
            else             v = fp[i - 3];
            h[j * Cc3 + i] = v;
        }
    }
    for (int i = lane; i < Cf; i += 64) g[C1 + i] = ff[qg * Cf + i];
    __syncthreads();

    for (int c0 = 0; c0 < C1; c0 += 64) {
        int c = c0 + lane;
        bool act = c < C1;
        float acc[K];
        float bias = act ? b1[c] : 0.0f;
#pragma unroll
        for (int j = 0; j < K; ++j) acc[j] = bias;
        for (int i = 0; i < Cc3; ++i) {
            float w = act ? W1[(size_t)i * C1 + c] : 0.0f;
#pragma unroll
            for (int j = 0; j < K; ++j) acc[j] = fmaf(h[j * Cc3 + i], w, acc[j]);
        }
        if (act) {
            float mv = acc[0];
#pragma unroll
            for (int j = 1; j < K; ++j) mv = fmaxf(mv, acc[j]);
            g[c] = fmaxf(mv, 0.0f);
        }
    }
    __syncthreads();

    const int Cg = C1 + Cf;
    for (int c0 = 0; c0 < C2; c0 += 64) {
        int c = c0 + lane;
        bool act = c < C2;
        float acc = act ? b2[c] : 0.0f;
        for (int i = 0; i < Cg; ++i) {
            float w = act ? W2[(size_t)i * C2 + c] : 0.0f;
            acc = fmaf(g[i], w, acc);
        }
        if (act) out[qg * C2 + c] = fmaxf(acc, 0.0f);
    }
}

// ---------------------------------------------------------------------------
// f0 = relu(feat @ d0_W + d0_b), 3 -> 32 channels.
// ---------------------------------------------------------------------------
__global__ void f0_kernel(const float* __restrict__ feat, const float* __restrict__ W,
                          const float* __restrict__ bias, float* __restrict__ out)
{
    int t = blockIdx.x * blockDim.x + threadIdx.x;
    int n = t >> 5, c = t & 31;
    const float* f = feat + (size_t)n * 3;
    float acc = bias[c];
    acc = fmaf(f[0], W[c], acc);
    acc = fmaf(f[1], W[32 + c], acc);
    acc = fmaf(f[2], W[64 + c], acc);
    out[t] = fmaxf(acc, 0.0f);
}

// ---------------------------------------------------------------------------

extern "C" void kernel_launch(void* const* d_in, const int* in_sizes, int n_in,
                              void* d_out, int out_size, void* d_ws, size_t ws_size,
                              hipStream_t stream)
{
    const float* pc    = (const float*)d_in[0];
    const float* feat  = (const float*)d_in[1];
    const float* d0_W  = (const float*)d_in[2];
    const float* d0_b  = (const float*)d_in[3];
    const float* d1_W0 = (const float*)d_in[4];
    const float* d1_b0 = (const float*)d_in[5];
    const float* d1_W1 = (const float*)d_in[6];
    const float* d1_b1 = (const float*)d_in[7];
    const float* d2_W0 = (const float*)d_in[8];
    const float* d2_b0 = (const float*)d_in[9];
    const float* d2_W1 = (const float*)d_in[10];
    const float* d2_b1 = (const float*)d_in[11];
    const float* d3_W0 = (const float*)d_in[12];
    const float* d3_b0 = (const float*)d_in[13];
    const float* d3_W1 = (const float*)d_in[14];
    const float* d3_b1 = (const float*)d_in[15];
    const float* d4_W0 = (const float*)d_in[16];
    const float* d4_b0 = (const float*)d_in[17];
    const float* d4_W1 = (const float*)d_in[18];
    const float* d4_b1 = (const float*)d_in[19];
    const float* u4_W1 = (const float*)d_in[20];
    const float* u4_b1 = (const float*)d_in[21];
    const float* u4_W2 = (const float*)d_in[22];
    const float* u4_b2 = (const float*)d_in[23];
    const float* u3_W1 = (const float*)d_in[24];
    const float* u3_b1 = (const float*)d_in[25];
    const float* u3_W2 = (const float*)d_in[26];
    const float* u3_b2 = (const float*)d_in[27];
    const float* u2_W1 = (const float*)d_in[28];
    const float* u2_b1 = (const float*)d_in[29];
    const float* u2_W2 = (const float*)d_in[30];
    const float* u2_b2 = (const float*)d_in[31];
    const float* u1_W1 = (const float*)d_in[32];
    const float* u1_b1 = (const float*)d_in[33];
    const float* u1_W2 = (const float*)d_in[34];
    const float* u1_b2 = (const float*)d_in[35];

    float* out = (float*)d_out;
    float* o_x1 = out + 0;       // 12288
    float* o_x2 = out + 12288;   // 3072
    float* o_x3 = out + 15360;   // 768
    float* o_i1 = out + 16128;   // 4096
    float* o_i2 = out + 20224;   // 1024
    float* o_i3 = out + 21248;   // 256
    float* o_u0 = out + 21504;   // 524288
    float* o_u1 = out + 545792;  // 262144
    float* o_u2 = out + 807936;  // 131072
    float* o_u3 = out + 939008;  // 49152

    float* w = (float*)d_ws;
    float* f0 = w; w += 2 * 8192 * 32;
    float* f1 = w; w += 2 * 2048 * 64;
    float* f2 = w; w += 2 * 512 * 128;
    float* f3 = w; w += 2 * 128 * 192;
    float* f4 = w; w += 2 * 64 * 192;
    float* x4 = w; w += 2 * 64 * 3;
    int* nidx = (int*)w;         // up to 2*8192*8 ints

    const int B = 2;
    const dim3 kb(64, KNN_QPB);

    // raise dynamic-LDS cap for the 128KB level-1 FPS (idempotent; gfx950 has
    // 160KB/CU). Not a stream op -> legal under graph capture.
    static bool attr_done = false;
    if (!attr_done) {
        (void)hipFuncSetAttribute((const void*)fps_block<256, 32>,
                                  hipFuncAttributeMaxDynamicSharedMemorySize,
                                  8192 * 3 * 4 + 2048 * 4 * 4);
        attr_done = true;
    }

    // f0
    f0_kernel<<<(2 * 8192 * 32) / 256, 256, 0, stream>>>(feat, d0_W, d0_b, f0);

    // ---- level 1: 8192 -> 2048, k=16, Cin=32, MLP 35->32->64
    fps_block<256, 32><<<B, 256, 8192 * 3 * 4 + 2048 * 4 * 4, stream>>>(pc, 2048, o_x1, o_i1);
    knn_wave<16><<<dim3(2048 / KNN_QPB, B), kb, 0, stream>>>(o_x1, 2048, pc, 8192, nidx);
    setconv_kernel<16><<<dim3(2048, B), 64, (16 * 35 + 16 * 32) * 4, stream>>>(
        pc, 8192, f0, 32, o_x1, 2048, nidx, d1_W0, d1_b0, 32, d1_W1, d1_b1, 64, f1);

    // ---- level 2: 2048 -> 512, Cin=64, MLP 67->64->128
    fps_block<256, 8><<<B, 256, 2048 * 3 * 4 + 512 * 4 * 4, stream>>>(o_x1, 512, o_x2, o_i2);
    knn_wave<16><<<dim3(512 / KNN_QPB, B), kb, 0, stream>>>(o_x2, 512, o_x1, 2048, nidx);
    setconv_kernel<16><<<dim3(512, B), 64, (16 * 67 + 16 * 64) * 4, stream>>>(
        o_x1, 2048, f1, 64, o_x2, 512, nidx, d2_W0, d2_b0, 64, d2_W1, d2_b1, 128, f2);

    // ---- level 3: 512 -> 128, Cin=128, MLP 131->128->192
    fps_wave<8><<<B, 64, 512 * 3 * 4 + 128 * 4 * 4, stream>>>(o_x2, 128, o_x3, o_i3);
    knn_wave<16><<<dim3(128 / KNN_QPB, B), kb, 0, stream>>>(o_x3, 128, o_x2, 512, nidx);
    setconv_kernel<16><<<dim3(128, B), 64, (16 * 131 + 16 * 128) * 4, stream>>>(
        o_x2, 512, f2, 128, o_x3, 128, nidx, d3_W0, d3_b0, 128, d3_W1, d3_b1, 192, f3);

    // ---- level 4: 128 -> 64, Cin=192, MLP 195->192->192
    fps_wave<2><<<B, 64, 128 * 3 * 4 + 64 * 4 * 4, stream>>>(o_x3, 64, x4, nullptr);
    knn_wave<16><<<dim3(64 / KNN_QPB, B), kb, 0, stream>>>(x4, 64, o_x3, 128, nidx);
    setconv_kernel<16><<<dim3(64, B), 64, (16 * 195 + 16 * 192) * 4, stream>>>(
        o_x3, 128, f3, 192, x4, 64, nidx, d4_W0, d4_b0, 192, d4_W1, d4_b1, 192, f4);

    // ---- u3: fine=x3(128), coarse=x4(64), cf=f4(192), ff=f3(192)
    knn_wave<8><<<dim3(128 / KNN_QPB, B), kb, 0, stream>>>(o_x3, 128, x4, 64, nidx);
    setupconv_kernel<8><<<dim3(128, B), 64, (8 * 195 + 192 + 192) * 4, stream>>>(
        x4, 64, f4, 192, o_x3, 128, f3, 192, nidx,
        u4_W1, u4_b1, 192, u4_W2, u4_b2, 192, o_u3);

    // ---- u2: fine=x2(512), coarse=x3(128), cf=u3(192), ff=f2(128)
    knn_wave<8><<<dim3(512 / KNN_QPB, B), kb, 0, stream>>>(o_x2, 512, o_x3, 128, nidx);
    setupconv_kernel<8><<<dim3(512, B), 64, (8 * 195 + 128 + 128) * 4, stream>>>(
        o_x3, 128, o_u3, 192, o_x2, 512, f2, 128, nidx,
        u3_W1, u3_b1, 128, u3_W2, u3_b2, 128, o_u2);

    // ---- u1: fine=x1(2048), coarse=x2(512), cf=u2(128), ff=f1(64)
    knn_wave<8><<<dim3(2048 / KNN_QPB, B), kb, 0, stream>>>(o_x1, 2048, o_x2, 512, nidx);
    setupconv_kernel<8><<<dim3(2048, B), 64, (8 * 131 + 64 + 64) * 4, stream>>>(
        o_x2, 512, o_u2, 128, o_x1, 2048, f1, 64, nidx,
        u2_W1, u2_b1, 64, u2_W2, u2_b2, 64, o_u1);

    // ---- u0: fine=pc(8192), coarse=x1(2048), cf=u1(64), ff=f0(32)
    knn_wave<8><<<dim3(8192 / KNN_QPB, B), kb, 0, stream>>>(pc, 8192, o_x1, 2048, nidx);
    setupconv_kernel<8><<<dim3(8192, B), 64, (8 * 67 + 32 + 32) * 4, stream>>>(
        o_x1, 2048, o_u1, 64, pc, 8192, f0, 32, nidx,
        u1_W1, u1_b1, 32, u1_W2, u1_b2, 32, o_u0);
}

// Round 8
// 3355.956 us; speedup vs baseline: 1.2995x; 1.0595x over previous
//
#include <hip/hip_runtime.h>
#include <cstdint>
#include <cstddef>

// ---------------------------------------------------------------------------
// FlowNet3D-style encoder/decoder pyramid (GenFlow_unit_mask).
// Round-8 structure: per-level KNN+conv fused into one kernel (wave-local
// KNN -> LDS -> conv), 13 dispatches total. FPS = round-5 best (1778us L1).
// ---------------------------------------------------------------------------

static __device__ __forceinline__ float sq3_rn(float x, float y, float z) {
    // ((x*x + y*y) + z*z) strict IEEE (no fma) to bit-match numpy
    return __fadd_rn(__fadd_rn(__fmul_rn(x, x), __fmul_rn(y, y)), __fmul_rn(z, z));
}

// monotone float -> uint map (handles negatives from catastrophic cancellation)
static __device__ __forceinline__ unsigned int ford(float f) {
    unsigned int u = __float_as_uint(f);
    return u ^ ((u >> 31) ? 0xFFFFFFFFu : 0x80000000u);
}

// ---------------------------------------------------------------------------
// Branchless DPP wave-64 u32 reductions. Result lands in lane 63.
// bound_ctrl=false -> invalid-source lanes keep old value (identity).
// ---------------------------------------------------------------------------
template <int CTRL>
static __device__ __forceinline__ void dpp_umax_step(unsigned& v) {
    unsigned t = (unsigned)__builtin_amdgcn_update_dpp((int)v, (int)v, CTRL, 0xf, 0xf, false);
    v = (t > v) ? t : v;   // v_max_u32
}
template <int CTRL>
static __device__ __forceinline__ void dpp_umin_step(unsigned& v) {
    unsigned t = (unsigned)__builtin_amdgcn_update_dpp((int)v, (int)v, CTRL, 0xf, 0xf, false);
    v = (t < v) ? t : v;   // v_min_u32
}
static __device__ __forceinline__ unsigned dpp_wave_umax(unsigned v) {
    dpp_umax_step<0x111>(v);  // row_shr:1
    dpp_umax_step<0x112>(v);  // row_shr:2
    dpp_umax_step<0x114>(v);  // row_shr:4
    dpp_umax_step<0x118>(v);  // row_shr:8
    dpp_umax_step<0x142>(v);  // row_bcast:15
    dpp_umax_step<0x143>(v);  // row_bcast:31
    return v;                 // full max in lane 63
}
static __device__ __forceinline__ unsigned dpp_wave_umin(unsigned v) {
    dpp_umin_step<0x111>(v);
    dpp_umin_step<0x112>(v);
    dpp_umin_step<0x114>(v);
    dpp_umin_step<0x118>(v);
    dpp_umin_step<0x142>(v);
    dpp_umin_step<0x143>(v);
    return v;
}

// Two-phase lexicographic (hi, lo) wave argmax/argmin. Exact tie-break.
static __device__ __forceinline__ void wave_argmax_u32pair(unsigned hi, unsigned lo,
                                                          unsigned& whi, unsigned& wlo) {
    unsigned h = dpp_wave_umax(hi);
    whi = (unsigned)__builtin_amdgcn_readlane((int)h, 63);
    unsigned cand = (hi == whi) ? lo : 0u;          // real lo > 0 always
    unsigned l = dpp_wave_umax(cand);
    wlo = (unsigned)__builtin_amdgcn_readlane((int)l, 63);
}
static __device__ __forceinline__ void wave_argmin_u32pair(unsigned hi, unsigned lo,
                                                          unsigned& whi, unsigned& wlo) {
    unsigned h = dpp_wave_umin(hi);
    whi = (unsigned)__builtin_amdgcn_readlane((int)h, 63);
    unsigned cand = (hi == whi) ? lo : 0xFFFFFFFFu; // real lo (index) < 2^31
    unsigned l = dpp_wave_umin(cand);
    wlo = (unsigned)__builtin_amdgcn_readlane((int)l, 63);
}

// ---------------------------------------------------------------------------
// FPS, multi-wave block version (round-5 best: 1778us at L1).
// Interleaved mapping p = j*T + t, full register residency, 4-way split
// accumulators, two-phase u32 reduce, LDS-accumulated outputs.
// Dynamic LDS = N*3*4 (mirror) + M*4*4 (out).
// ---------------------------------------------------------------------------
template <int T, int P>
__global__ __launch_bounds__(T) __attribute__((amdgpu_waves_per_eu(1, 1)))
void fps_block(const float* __restrict__ xyz, int M,
               float* __restrict__ new_xyz, float* __restrict__ out_idx)
{
    static_assert(P % 4 == 0, "P must be a multiple of 4");
    constexpr int N = T * P;
    constexpr int NW = T / 64;
    constexpr int Q = P / 4;
    const int b = blockIdx.x;
    const int t = threadIdx.x;
    const int lane = t & 63, wave = t >> 6;

    __shared__ uint2 s_slot[2][NW];   // {hi, lo} per wave, parity-buffered
    extern __shared__ float sm[];
    float* spts = sm;           // N*3 point mirror
    float* sout = sm + N * 3;   // M*4: cx,cy,cz,(float)idx

    const float* x0 = xyz + (size_t)b * N * 3;
    for (int i = t; i < N * 3; i += T) spts[i] = x0[i];

    float px[P], py[P], pz[P], dist[P];
#pragma unroll
    for (int j = 0; j < P; ++j) {
        int p = j * T + t;
        px[j] = x0[p * 3 + 0];
        py[j] = x0[p * 3 + 1];
        pz[j] = x0[p * 3 + 2];
        dist[j] = 1e10f;
    }
    __syncthreads();

    int far = 0;
    for (int m = 0; m < M; ++m) {
        float cx = spts[far * 3 + 0];
        float cy = spts[far * 3 + 1];
        float cz = spts[far * 3 + 2];
        if (t == 0) {
            float* so = sout + m * 4;
            so[0] = cx; so[1] = cy; so[2] = cz; so[3] = (float)far;
        }
        float bv[4]; int bj[4];
#pragma unroll
        for (int a = 0; a < 4; ++a) { bv[a] = -1.0f; bj[a] = 0; }
#pragma unroll
        for (int j = 0; j < Q; ++j) {
#pragma unroll
            for (int a = 0; a < 4; ++a) {
                int jj = a * Q + j;
                float dx = __fsub_rn(px[jj], cx);
                float dy = __fsub_rn(py[jj], cy);
                float dz = __fsub_rn(pz[jj], cz);
                float d  = sq3_rn(dx, dy, dz);
                float nd = fminf(dist[jj], d);
                dist[jj] = nd;
                bj[a] = (nd > bv[a]) ? jj : bj[a];   // strict >: first occurrence
                bv[a] = fmaxf(bv[a], nd);
            }
        }
        float bvv = bv[0]; int bjj = bj[0];
#pragma unroll
        for (int a = 1; a < 4; ++a) {
            bjj = (bv[a] > bvv) ? bj[a] : bjj;       // tie keeps lower quarter
            bvv = fmaxf(bvv, bv[a]);
        }
        int bp = bjj * T + t;
        unsigned hi = __float_as_uint(bvv);          // bvv >= 0 -> monotone bits
        unsigned lo = 0x7fffffffu - (unsigned)bp;    // larger lo = smaller idx
        unsigned whi, wlo;
        wave_argmax_u32pair(hi, lo, whi, wlo);
        if (lane == 0) s_slot[m & 1][wave] = make_uint2(whi, wlo);
        __syncthreads();
        uint2 sv[NW];
#pragma unroll
        for (int w2 = 0; w2 < NW; ++w2) sv[w2] = s_slot[m & 1][w2];
        unsigned bhi = 0u, blo = 0u;
#pragma unroll
        for (int w2 = 0; w2 < NW; ++w2) bhi = (sv[w2].x > bhi) ? sv[w2].x : bhi;
#pragma unroll
        for (int w2 = 0; w2 < NW; ++w2) {
            unsigned c = (sv[w2].x == bhi) ? sv[w2].y : 0u;
            blo = (c > blo) ? c : blo;
        }
        far = 0x7fffffff - (int)blo;
    }

    __syncthreads();
    for (int i = t; i < M * 3; i += T) {
        int mm = i / 3, c = i - mm * 3;
        new_xyz[(size_t)b * M * 3 + i] = sout[mm * 4 + c];
    }
    if (out_idx) {
        for (int i = t; i < M; i += T)
            out_idx[(size_t)b * M + i] = sout[i * 4 + 3];
    }
}

// ---------------------------------------------------------------------------
// FPS, single-wave version (round-5): thread-major mapping, split
// accumulators, single-phase DPP + ballot (min lane = min idx, exact).
// ---------------------------------------------------------------------------
template <int P>
__global__ __launch_bounds__(64) __attribute__((amdgpu_waves_per_eu(1, 1)))
void fps_wave(const float* __restrict__ xyz, int M,
              float* __restrict__ new_xyz, float* __restrict__ out_idx)
{
    constexpr int NA = (P % 4 == 0) ? 4 : 2;
    constexpr int Q = P / NA;
    const int b = blockIdx.x;
    const int lane = threadIdx.x;
    const int N = 64 * P;
    extern __shared__ float sm[];
    float* spts = sm;           // N*3
    float* sout = sm + N * 3;   // M*4
    const float* x0 = xyz + (size_t)b * N * 3;

    for (int i = lane; i < N * 3; i += 64) spts[i] = x0[i];

    float px[P], py[P], pz[P], dist[P];
#pragma unroll
    for (int j = 0; j < P; ++j) {
        int p = lane * P + j;       // thread-major
        px[j] = x0[p * 3 + 0];
        py[j] = x0[p * 3 + 1];
        pz[j] = x0[p * 3 + 2];
        dist[j] = 1e10f;
    }
    __syncthreads();

    int far = 0;
    for (int m = 0; m < M; ++m) {
        float cx = spts[far * 3 + 0];
        float cy = spts[far * 3 + 1];
        float cz = spts[far * 3 + 2];
        if (lane == 0) {
            float* so = sout + m * 4;
            so[0] = cx; so[1] = cy; so[2] = cz; so[3] = (float)far;
        }
        float bv[NA]; int bj[NA];
#pragma unroll
        for (int a = 0; a < NA; ++a) { bv[a] = -1.0f; bj[a] = 0; }
#pragma unroll
        for (int j = 0; j < Q; ++j) {
#pragma unroll
            for (int a = 0; a < NA; ++a) {
                int idx = a * Q + j;
                float dx = __fsub_rn(px[idx], cx);
                float dy = __fsub_rn(py[idx], cy);
                float dz = __fsub_rn(pz[idx], cz);
                float d  = sq3_rn(dx, dy, dz);
                float nd = fminf(dist[idx], d);
                dist[idx] = nd;
                bj[a] = (nd > bv[a]) ? idx : bj[a];
                bv[a] = fmaxf(bv[a], nd);
            }
        }
        float bvv = bv[0]; int bjj = bj[0];
#pragma unroll
        for (int a = 1; a < NA; ++a) {
            bjj = (bv[a] > bvv) ? bj[a] : bjj;
            bvv = fmaxf(bvv, bv[a]);
        }
        unsigned hi = __float_as_uint(bvv);
        unsigned h = dpp_wave_umax(hi);
        unsigned whi = (unsigned)__builtin_amdgcn_readlane((int)h, 63);
        unsigned long long mk = __ballot(hi == whi);
        int L = (int)__builtin_ctzll(mk);           // min lane = min point idx
        int bjL = __builtin_amdgcn_readlane(bjj, L);
        far = L * P + bjL;
    }

    __syncthreads();
    for (int i = lane; i < M * 3; i += 64) {
        int mm = i / 3, c = i - mm * 3;
        new_xyz[(size_t)b * M * 3 + i] = sout[mm * 4 + c];
    }
    if (out_idx) {
        for (int i = lane; i < M; i += 64)
            out_idx[(size_t)b * M + i] = sout[i * 4 + 3];
    }
}

// ---------------------------------------------------------------------------
// FUSED KNN + SetConv. 256-thread block = 4 waves = 4 queries.
// Wave ty computes the exact knn_wave top-K for its query into LDS, then
// runs the setconv MLP for the same query (per-wave LDS slices). Same math
// and ordering as the previous split kernels; nidx never touches global.
// LDS: int nidx[4][K]; float h[4][K*Cin3]; float h1[4][K*C1].
// Requires M % 4 == 0 (all levels satisfy this).
// ---------------------------------------------------------------------------
template <int K>
__global__ __launch_bounds__(256)
void setconv_full(const float* __restrict__ ref_xyz, int N,
                  const float* __restrict__ ref_feat, int Cin,
                  const float* __restrict__ new_xyz, int M,
                  const float* __restrict__ W0, const float* __restrict__ b0, int C1,
                  const float* __restrict__ W1, const float* __restrict__ b1, int C2,
                  float* __restrict__ out)
{
    const int b = blockIdx.y;
    const int tid = threadIdx.x;
    const int lane = tid & 63, ty = tid >> 6;
    const int m = blockIdx.x * 4 + ty;
    const int Cin3 = Cin + 3;

    extern __shared__ float sm[];
    int*   nidx_s = (int*)sm;                 // [4][K]
    float* hb  = sm + 4 * K;                  // [4][K*Cin3]
    float* h1b = hb + 4 * K * Cin3;           // [4][K*C1]
    float* h  = hb  + ty * K * Cin3;
    float* h1 = h1b + ty * K * C1;

    const size_t qg = (size_t)b * M + m;
    const float* qp = new_xyz + qg * 3;
    const float qx = qp[0], qy = qp[1], qz = qp[2];

    // ---- KNN phase (exact knn_wave body) ----
    {
        const float sq = sq3_rn(qx, qy, qz);
        float dk[K]; int ik[K];
#pragma unroll
        for (int j = 0; j < K; ++j) { dk[j] = INFINITY; ik[j] = 0x7fffffff; }
        const float* rb = ref_xyz + (size_t)b * N * 3;
        for (int n = lane; n < N; n += 64) {
            const float* rp = rb + (size_t)n * 3;
            float rx = rp[0], ry = rp[1], rz = rp[2];
            float sr = sq3_rn(rx, ry, rz);
            float dot = __fadd_rn(__fadd_rn(__fmul_rn(qx, rx), __fmul_rn(qy, ry)),
                                  __fmul_rn(qz, rz));
            float d = __fadd_rn(__fsub_rn(sq, __fmul_rn(2.0f, dot)), sr);
            if (d < dk[K - 1]) {
                dk[K - 1] = d;
                ik[K - 1] = n;
#pragma unroll
                for (int j = K - 1; j > 0; --j) {
                    if (dk[j] < dk[j - 1]) {
                        float tv = dk[j]; dk[j] = dk[j - 1]; dk[j - 1] = tv;
                        int   ti = ik[j]; ik[j] = ik[j - 1]; ik[j - 1] = ti;
                    }
                }
            }
        }
        unsigned hiA[K], loA[K];
#pragma unroll
        for (int j = 0; j < K; ++j) { hiA[j] = ford(dk[j]); loA[j] = (unsigned)ik[j]; }
        int winner = 0;
        for (int r = 0; r < K; ++r) {
            unsigned bhi, blo;
            wave_argmin_u32pair(hiA[0], loA[0], bhi, blo);
            if (lane == r) winner = (int)blo;
            if (hiA[0] == bhi && loA[0] == blo) {
#pragma unroll
                for (int j = 0; j < K - 1; ++j) { hiA[j] = hiA[j + 1]; loA[j] = loA[j + 1]; }
                hiA[K - 1] = 0xFFFFFFFFu;
                loA[K - 1] = 0xFFFFFFFFu;
            }
        }
        if (lane < K) nidx_s[ty * K + lane] = winner;
    }
    __syncthreads();

    // ---- gather phase ----
    for (int j = 0; j < K; ++j) {
        int n = nidx_s[ty * K + j];
        const float* xp = ref_xyz + ((size_t)b * N + n) * 3;
        const float* fp = ref_feat + ((size_t)b * N + n) * Cin;
        for (int i = lane; i < Cin3; i += 64) {
            float v;
            if (i == 0)      v = __fsub_rn(xp[0], qx);
            else if (i == 1) v = __fsub_rn(xp[1], qy);
            else if (i == 2) v = __fsub_rn(xp[2], qz);
            else             v = fp[i - 3];
            h[j * Cin3 + i] = v;
        }
    }
    __syncthreads();

    // ---- MLP layer 1 ----
    for (int c0 = 0; c0 < C1; c0 += 64) {
        int c = c0 + lane;
        bool act = c < C1;
        float acc[K];
        float bias = act ? b0[c] : 0.0f;
#pragma unroll
        for (int j = 0; j < K; ++j) acc[j] = bias;
        for (int i = 0; i < Cin3; ++i) {
            float w = act ? W0[(size_t)i * C1 + c] : 0.0f;
#pragma unroll
            for (int j = 0; j < K; ++j) acc[j] = fmaf(h[j * Cin3 + i], w, acc[j]);
        }
        if (act) {
#pragma unroll
            for (int j = 0; j < K; ++j) h1[j * C1 + c] = fmaxf(acc[j], 0.0f);
        }
    }
    __syncthreads();

    // ---- MLP layer 2 + max-pool ----
    for (int c0 = 0; c0 < C2; c0 += 64) {
        int c = c0 + lane;
        bool act = c < C2;
        float acc[K];
        float bias = act ? b1[c] : 0.0f;
#pragma unroll
        for (int j = 0; j < K; ++j) acc[j] = bias;
        for (int i = 0; i < C1; ++i) {
            float w = act ? W1[(size_t)i * C2 + c] : 0.0f;
#pragma unroll
            for (int j = 0; j < K; ++j) acc[j] = fmaf(h1[j * C1 + i], w, acc[j]);
        }
        if (act) {
            float mv = acc[0];
#pragma unroll
            for (int j = 1; j < K; ++j) mv = fmaxf(mv, acc[j]);
            out[qg * C2 + c] = fmaxf(mv, 0.0f);
        }
    }
}

// ---------------------------------------------------------------------------
// FUSED KNN + SetUpConv. Same structure: 4 waves = 4 fine queries.
// LDS: int nidx[4][K]; float h[4][K*Cc3]; float g[4][C1+Cf].
// ---------------------------------------------------------------------------
template <int K>
__global__ __launch_bounds__(256)
void upconv_full(const float* __restrict__ cxyz, int Nc,
                 const float* __restrict__ cf, int Cc,
                 const float* __restrict__ fxyz, int M,
                 const float* __restrict__ ff, int Cf,
                 const float* __restrict__ W1, const float* __restrict__ b1, int C1,
                 const float* __restrict__ W2, const float* __restrict__ b2, int C2,
                 float* __restrict__ out)
{
    const int b = blockIdx.y;
    const int tid = threadIdx.x;
    const int lane = tid & 63, ty = tid >> 6;
    const int m = blockIdx.x * 4 + ty;
    const int Cc3 = Cc + 3;

    extern __shared__ float sm[];
    int*   nidx_s = (int*)sm;                 // [4][K]
    float* hb = sm + 4 * K;                   // [4][K*Cc3]
    float* gb = hb + 4 * K * Cc3;             // [4][C1+Cf]
    float* h = hb + ty * K * Cc3;
    float* g = gb + ty * (C1 + Cf);

    const size_t qg = (size_t)b * M + m;
    const float* qp = fxyz + qg * 3;
    const float qx = qp[0], qy = qp[1], qz = qp[2];

    // ---- KNN phase ----
    {
        const float sq = sq3_rn(qx, qy, qz);
        float dk[K]; int ik[K];
#pragma unroll
        for (int j = 0; j < K; ++j) { dk[j] = INFINITY; ik[j] = 0x7fffffff; }
        const float* rb = cxyz + (size_t)b * Nc * 3;
        for (int n = lane; n < Nc; n += 64) {
            const float* rp = rb + (size_t)n * 3;
            float rx = rp[0], ry = rp[1], rz = rp[2];
            float sr = sq3_rn(rx, ry, rz);
            float dot = __fadd_rn(__fadd_rn(__fmul_rn(qx, rx), __fmul_rn(qy, ry)),
                                  __fmul_rn(qz, rz));
            float d = __fadd_rn(__fsub_rn(sq, __fmul_rn(2.0f, dot)), sr);
            if (d < dk[K - 1]) {
                dk[K - 1] = d;
                ik[K - 1] = n;
#pragma unroll
                for (int j = K - 1; j > 0; --j) {
                    if (dk[j] < dk[j - 1]) {
                        float tv = dk[j]; dk[j] = dk[j - 1]; dk[j - 1] = tv;
                        int   ti = ik[j]; ik[j] = ik[j - 1]; ik[j - 1] = ti;
                    }
                }
            }
        }
        unsigned hiA[K], loA[K];
#pragma unroll
        for (int j = 0; j < K; ++j) { hiA[j] = ford(dk[j]); loA[j] = (unsigned)ik[j]; }
        int winner = 0;
        for (int r = 0; r < K; ++r) {
            unsigned bhi, blo;
            wave_argmin_u32pair(hiA[0], loA[0], bhi, blo);
            if (lane == r) winner = (int)blo;
            if (hiA[0] == bhi && loA[0] == blo) {
#pragma unroll
                for (int j = 0; j < K - 1; ++j) { hiA[j] = hiA[j + 1]; loA[j] = loA[j + 1]; }
                hiA[K - 1] = 0xFFFFFFFFu;
                loA[K - 1] = 0xFFFFFFFFu;
            }
        }
        if (lane < K) nidx_s[ty * K + lane] = winner;
    }
    __syncthreads();

    // ---- gather phase ----
    for (int j = 0; j < K; ++j) {
        int n = nidx_s[ty * K + j];
        const float* xp = cxyz + ((size_t)b * Nc + n) * 3;
        const float* fp = cf + ((size_t)b * Nc + n) * Cc;
        for (int i = lane; i < Cc3; i += 64) {
            float v;
            if (i == 0)      v = __fsub_rn(xp[0], qx);
            else if (i == 1) v = __fsub_rn(xp[1], qy);
            else if (i == 2) v = __fsub_rn(xp[2], qz);
            else             v = fp[i - 3];
            h[j * Cc3 + i] = v;
        }
    }
    for (int i = lane; i < Cf; i += 64) g[C1 + i] = ff[qg * Cf + i];
    __syncthreads();

    // ---- MLP1 + max-pool ----
    for (int c0 = 0; c0 < C1; c0 += 64) {
        int c = c0 + lane;
        bool act = c < C1;
        float acc[K];
        float bias = act ? b1[c] : 0.0f;
#pragma unroll
        for (int j = 0; j < K; ++j) acc[j] = bias;
        for (int i = 0; i < Cc3; ++i) {
            float w = act ? W1[(size_t)i * C1 + c] : 0.0f;
#pragma unroll
            for (int j = 0; j < K; ++j) acc[j] = fmaf(h[j * Cc3 + i], w, acc[j]);
        }
        if (act) {
            float mv = acc[0];
#pragma unroll
            for (int j = 1; j < K; ++j) mv = fmaxf(mv, acc[j]);
            g[c] = fmaxf(mv, 0.0f);
        }
    }
    __syncthreads();

    // ---- MLP2 on [pooled, ff] ----
    const int Cg = C1 + Cf;
    for (int c0 = 0; c0 < C2; c0 += 64) {
        int c = c0 + lane;
        bool act = c < C2;
        float acc = act ? b2[c] : 0.0f;
        for (int i = 0; i < Cg; ++i) {
            float w = act ? W2[(size_t)i * C2 + c] : 0.0f;
            acc = fmaf(g[i], w, acc);
        }
        if (act) out[qg * C2 + c] = fmaxf(acc, 0.0f);
    }
}

// ---------------------------------------------------------------------------
// f0 = relu(feat @ d0_W + d0_b), 3 -> 32 channels.
// ---------------------------------------------------------------------------
__global__ void f0_kernel(const float* __restrict__ feat, const float* __restrict__ W,
                          const float* __restrict__ bias, float* __restrict__ out)
{
    int t = blockIdx.x * blockDim.x + threadIdx.x;
    int n = t >> 5, c = t & 31;
    const float* f = feat + (size_t)n * 3;
    float acc = bias[c];
    acc = fmaf(f[0], W[c], acc);
    acc = fmaf(f[1], W[32 + c], acc);
    acc = fmaf(f[2], W[64 + c], acc);
    out[t] = fmaxf(acc, 0.0f);
}

// ---------------------------------------------------------------------------

extern "C" void kernel_launch(void* const* d_in, const int* in_sizes, int n_in,
                              void* d_out, int out_size, void* d_ws, size_t ws_size,
                              hipStream_t stream)
{
    const float* pc    = (const float*)d_in[0];
    const float* feat  = (const float*)d_in[1];
    const float* d0_W  = (const float*)d_in[2];
    const float* d0_b  = (const float*)d_in[3];
    const float* d1_W0 = (const float*)d_in[4];
    const float* d1_b0 = (const float*)d_in[5];
    const float* d1_W1 = (const float*)d_in[6];
    const float* d1_b1 = (const float*)d_in[7];
    const float* d2_W0 = (const float*)d_in[8];
    const float* d2_b0 = (const float*)d_in[9];
    const float* d2_W1 = (const float*)d_in[10];
    const float* d2_b1 = (const float*)d_in[11];
    const float* d3_W0 = (const float*)d_in[12];
    const float* d3_b0 = (const float*)d_in[13];
    const float* d3_W1 = (const float*)d_in[14];
    const float* d3_b1 = (const float*)d_in[15];
    const float* d4_W0 = (const float*)d_in[16];
    const float* d4_b0 = (const float*)d_in[17];
    const float* d4_W1 = (const float*)d_in[18];
    const float* d4_b1 = (const float*)d_in[19];
    const float* u4_W1 = (const float*)d_in[20];
    const float* u4_b1 = (const float*)d_in[21];
    const float* u4_W2 = (const float*)d_in[22];
    const float* u4_b2 = (const float*)d_in[23];
    const float* u3_W1 = (const float*)d_in[24];
    const float* u3_b1 = (const float*)d_in[25];
    const float* u3_W2 = (const float*)d_in[26];
    const float* u3_b2 = (const float*)d_in[27];
    const float* u2_W1 = (const float*)d_in[28];
    const float* u2_b1 = (const float*)d_in[29];
    const float* u2_W2 = (const float*)d_in[30];
    const float* u2_b2 = (const float*)d_in[31];
    const float* u1_W1 = (const float*)d_in[32];
    const float* u1_b1 = (const float*)d_in[33];
    const float* u1_W2 = (const float*)d_in[34];
    const float* u1_b2 = (const float*)d_in[35];

    float* out = (float*)d_out;
    float* o_x1 = out + 0;       // 12288
    float* o_x2 = out + 12288;   // 3072
    float* o_x3 = out + 15360;   // 768
    float* o_i1 = out + 16128;   // 4096
    float* o_i2 = out + 20224;   // 1024
    float* o_i3 = out + 21248;   // 256
    float* o_u0 = out + 21504;   // 524288
    float* o_u1 = out + 545792;  // 262144
    float* o_u2 = out + 807936;  // 131072
    float* o_u3 = out + 939008;  // 49152

    float* w = (float*)d_ws;
    float* f0 = w; w += 2 * 8192 * 32;
    float* f1 = w; w += 2 * 2048 * 64;
    float* f2 = w; w += 2 * 512 * 128;
    float* f3 = w; w += 2 * 128 * 192;
    float* f4 = w; w += 2 * 64 * 192;
    float* x4 = w; w += 2 * 64 * 3;

    const int B = 2;

    // raise dynamic-LDS caps (idempotent; gfx950 has 160KB/CU).
    static bool attr_done = false;
    if (!attr_done) {
        (void)hipFuncSetAttribute((const void*)fps_block<256, 32>,
                                  hipFuncAttributeMaxDynamicSharedMemorySize,
                                  8192 * 3 * 4 + 2048 * 4 * 4);         // 131072
        (void)hipFuncSetAttribute((const void*)setconv_full<16>,
                                  hipFuncAttributeMaxDynamicSharedMemorySize,
                                  (4 * 16 + 4 * 16 * 195 + 4 * 16 * 192) * 4); // 99328 (L4 worst case)
        attr_done = true;
    }

    // f0
    f0_kernel<<<(2 * 8192 * 32) / 256, 256, 0, stream>>>(feat, d0_W, d0_b, f0);

    // ---- coordinate pyramid (FPS chain) ----
    fps_block<256, 32><<<B, 256, 8192 * 3 * 4 + 2048 * 4 * 4, stream>>>(pc, 2048, o_x1, o_i1);
    fps_block<256, 8><<<B, 256, 2048 * 3 * 4 + 512 * 4 * 4, stream>>>(o_x1, 512, o_x2, o_i2);
    fps_wave<8><<<B, 64, 512 * 3 * 4 + 128 * 4 * 4, stream>>>(o_x2, 128, o_x3, o_i3);
    fps_wave<2><<<B, 64, 128 * 3 * 4 + 64 * 4 * 4, stream>>>(o_x3, 64, x4, nullptr);

    // ---- feature pyramid down (fused knn+setconv) ----
    setconv_full<16><<<dim3(2048 / 4, B), 256, (4 * 16 + 4 * 16 * 35 + 4 * 16 * 32) * 4, stream>>>(
        pc, 8192, f0, 32, o_x1, 2048, d1_W0, d1_b0, 32, d1_W1, d1_b1, 64, f1);
    setconv_full<16><<<dim3(512 / 4, B), 256, (4 * 16 + 4 * 16 * 67 + 4 * 16 * 64) * 4, stream>>>(
        o_x1, 2048, f1, 64, o_x2, 512, d2_W0, d2_b0, 64, d2_W1, d2_b1, 128, f2);
    setconv_full<16><<<dim3(128 / 4, B), 256, (4 * 16 + 4 * 16 * 131 + 4 * 16 * 128) * 4, stream>>>(
        o_x2, 512, f2, 128, o_x3, 128, d3_W0, d3_b0, 128, d3_W1, d3_b1, 192, f3);
    setconv_full<16><<<dim3(64 / 4, B), 256, (4 * 16 + 4 * 16 * 195 + 4 * 16 * 192) * 4, stream>>>(
        o_x3, 128, f3, 192, x4, 64, d4_W0, d4_b0, 192, d4_W1, d4_b1, 192, f4);

    // ---- feature pyramid up (fused knn+setupconv) ----
    upconv_full<8><<<dim3(128 / 4, B), 256, (4 * 8 + 4 * 8 * 195 + 4 * (192 + 192)) * 4, stream>>>(
        x4, 64, f4, 192, o_x3, 128, f3, 192,
        u4_W1, u4_b1, 192, u4_W2, u4_b2, 192, o_u3);
    upconv_full<8><<<dim3(512 / 4, B), 256, (4 * 8 + 4 * 8 * 195 + 4 * (128 + 128)) * 4, stream>>>(
        o_x3, 128, o_u3, 192, o_x2, 512, f2, 128,
        u3_W1, u3_b1, 128, u3_W2, u3_b2, 128, o_u2);
    upconv_full<8><<<dim3(2048 / 4, B), 256, (4 * 8 + 4 * 8 * 131 + 4 * (64 + 64)) * 4, stream>>>(
        o_x2, 512, o_u2, 128, o_x1, 2048, f1, 64,
        u2_W1, u2_b1, 64, u2_W2, u2_b2, 64, o_u1);
    upconv_full<8><<<dim3(8192 / 4, B), 256, (4 * 8 + 4 * 8 * 67 + 4 * (32 + 32)) * 4, stream>>>(
        o_x1, 2048, o_u1, 64, pc, 8192, f0, 32,
        u1_W1, u1_b1, 32, u1_W2, u1_b2, 32, o_u0);
}

// Round 10
// 2917.408 us; speedup vs baseline: 1.4949x; 1.1503x over previous
//
#include <hip/hip_runtime.h>
#include <cstdint>
#include <cstddef>

// ---------------------------------------------------------------------------
// FlowNet3D-style encoder/decoder pyramid (GenFlow_unit_mask).
// Round-9 (resubmit; prior run died to container-acquisition failure):
// round-5 exact FPS (thread-major+ballot, 1778us) + fused knn/conv kernels
// with ALL channel dims as template params (kills scratch spill: r0/r7
// counters showed VGPR=24 + GB-scale FETCH on conv kernels).
// ---------------------------------------------------------------------------

static __device__ __forceinline__ float sq3_rn(float x, float y, float z) {
    // ((x*x + y*y) + z*z) strict IEEE (no fma) to bit-match numpy
    return __fadd_rn(__fadd_rn(__fmul_rn(x, x), __fmul_rn(y, y)), __fmul_rn(z, z));
}

// monotone float -> uint map (handles negatives from catastrophic cancellation)
static __device__ __forceinline__ unsigned int ford(float f) {
    unsigned int u = __float_as_uint(f);
    return u ^ ((u >> 31) ? 0xFFFFFFFFu : 0x80000000u);
}

// ---------------------------------------------------------------------------
// Branchless DPP wave-64 u32 reductions. Result lands in lane 63.
// bound_ctrl=false -> invalid-source lanes keep old value (identity).
// ---------------------------------------------------------------------------
template <int CTRL>
static __device__ __forceinline__ void dpp_umax_step(unsigned& v) {
    unsigned t = (unsigned)__builtin_amdgcn_update_dpp((int)v, (int)v, CTRL, 0xf, 0xf, false);
    v = (t > v) ? t : v;   // v_max_u32
}
template <int CTRL>
static __device__ __forceinline__ void dpp_umin_step(unsigned& v) {
    unsigned t = (unsigned)__builtin_amdgcn_update_dpp((int)v, (int)v, CTRL, 0xf, 0xf, false);
    v = (t < v) ? t : v;   // v_min_u32
}
static __device__ __forceinline__ unsigned dpp_wave_umax(unsigned v) {
    dpp_umax_step<0x111>(v);  // row_shr:1
    dpp_umax_step<0x112>(v);  // row_shr:2
    dpp_umax_step<0x114>(v);  // row_shr:4
    dpp_umax_step<0x118>(v);  // row_shr:8
    dpp_umax_step<0x142>(v);  // row_bcast:15
    dpp_umax_step<0x143>(v);  // row_bcast:31
    return v;                 // full max in lane 63
}
static __device__ __forceinline__ unsigned dpp_wave_umin(unsigned v) {
    dpp_umin_step<0x111>(v);
    dpp_umin_step<0x112>(v);
    dpp_umin_step<0x114>(v);
    dpp_umin_step<0x118>(v);
    dpp_umin_step<0x142>(v);
    dpp_umin_step<0x143>(v);
    return v;
}
static __device__ __forceinline__ void wave_argmin_u32pair(unsigned hi, unsigned lo,
                                                          unsigned& whi, unsigned& wlo) {
    unsigned h = dpp_wave_umin(hi);
    whi = (unsigned)__builtin_amdgcn_readlane((int)h, 63);
    unsigned cand = (hi == whi) ? lo : 0xFFFFFFFFu; // real lo (index) < 2^31
    unsigned l = dpp_wave_umin(cand);
    wlo = (unsigned)__builtin_amdgcn_readlane((int)l, 63);
}

// ---------------------------------------------------------------------------
// FPS, multi-wave block version (round-5 exact: 1778us at L1).
// THREAD-MAJOR mapping: thread t owns points [t*P, (t+1)*P). Within a wave,
// smaller lane => strictly smaller point indices, so among value-ties the
// FIRST matching lane (ballot+ctz) is the exact numpy first-occurrence.
// Per-thread scan: 4 independent accumulators over contiguous quarters.
// Wave reduce = ONE 6-step DPP u32-max + readlane + ballot + readlane(bj,L).
// Cross-wave merge: max hi, min bp among matches (wave ranges disjoint).
// Zero global ops in the serial loop; ONE barrier/iter (parity slots).
// Dynamic LDS = N*3*4 (mirror) + M*4*4 (out).
// ---------------------------------------------------------------------------
template <int T, int P>
__global__ __launch_bounds__(T) __attribute__((amdgpu_waves_per_eu(1, 1)))
void fps_block(const float* __restrict__ xyz, int M,
               float* __restrict__ new_xyz, float* __restrict__ out_idx)
{
    static_assert(P % 4 == 0, "P must be a multiple of 4");
    constexpr int N = T * P;
    constexpr int NW = T / 64;
    constexpr int Q = P / 4;
    const int b = blockIdx.x;
    const int t = threadIdx.x;
    const int lane = t & 63, wave = t >> 6;

    __shared__ uint2 s_slot[2][NW];   // {hi, bp} per wave, parity-buffered
    extern __shared__ float sm[];
    float* spts = sm;           // N*3 point mirror
    float* sout = sm + N * 3;   // M*4: cx,cy,cz,(float)idx

    const float* x0 = xyz + (size_t)b * N * 3;
    for (int i = t; i < N * 3; i += T) spts[i] = x0[i];

    float px[P], py[P], pz[P], dist[P];
#pragma unroll
    for (int j = 0; j < P; ++j) {
        int p = t * P + j;          // thread-major
        px[j] = x0[p * 3 + 0];
        py[j] = x0[p * 3 + 1];
        pz[j] = x0[p * 3 + 2];
        dist[j] = 1e10f;
    }
    __syncthreads();

    int far = 0;
    for (int m = 0; m < M; ++m) {
        float cx = spts[far * 3 + 0];
        float cy = spts[far * 3 + 1];
        float cz = spts[far * 3 + 2];
        if (t == 0) {
            float* so = sout + m * 4;
            so[0] = cx; so[1] = cy; so[2] = cz; so[3] = (float)far;
        }
        float bv[4]; int bj[4];
#pragma unroll
        for (int a = 0; a < 4; ++a) { bv[a] = -1.0f; bj[a] = 0; }
#pragma unroll
        for (int j = 0; j < Q; ++j) {
#pragma unroll
            for (int a = 0; a < 4; ++a) {
                int idx = a * Q + j;
                float dx = __fsub_rn(px[idx], cx);
                float dy = __fsub_rn(py[idx], cy);
                float dz = __fsub_rn(pz[idx], cz);
                float d  = sq3_rn(dx, dy, dz);
                float nd = fminf(dist[idx], d);
                dist[idx] = nd;
                bj[a] = (nd > bv[a]) ? idx : bj[a];   // strict >: first occurrence
                bv[a] = fmaxf(bv[a], nd);
            }
        }
        float bvv = bv[0]; int bjj = bj[0];
#pragma unroll
        for (int a = 1; a < 4; ++a) {
            bjj = (bv[a] > bvv) ? bj[a] : bjj;        // tie keeps lower quarter
            bvv = fmaxf(bvv, bv[a]);
        }
        unsigned hi = __float_as_uint(bvv);           // bvv >= 0 -> monotone bits
        unsigned h = dpp_wave_umax(hi);
        unsigned whi = (unsigned)__builtin_amdgcn_readlane((int)h, 63);
        unsigned long long mk = __ballot(hi == whi);  // nonempty (max matches self)
        int L = (int)__builtin_ctzll(mk);             // min lane = min point idx
        int bjL = __builtin_amdgcn_readlane(bjj, L);
        unsigned wbp = (unsigned)((((wave << 6) + L) * P) + bjL);
        if (lane == 0) s_slot[m & 1][wave] = make_uint2(whi, wbp);
        __syncthreads();
        uint2 sv[NW];
#pragma unroll
        for (int w2 = 0; w2 < NW; ++w2) sv[w2] = s_slot[m & 1][w2];
        unsigned bhi = 0u;
#pragma unroll
        for (int w2 = 0; w2 < NW; ++w2) bhi = (sv[w2].x > bhi) ? sv[w2].x : bhi;
        unsigned blo = 0xFFFFFFFFu;
#pragma unroll
        for (int w2 = 0; w2 < NW; ++w2) {
            unsigned c = (sv[w2].x == bhi) ? sv[w2].y : 0xFFFFFFFFu;
            blo = (c < blo) ? c : blo;                // wave ranges disjoint+ordered
        }
        far = (int)blo;
    }

    // coalesced flush of accumulated outputs
    __syncthreads();
    for (int i = t; i < M * 3; i += T) {
        int mm = i / 3, c = i - mm * 3;
        new_xyz[(size_t)b * M * 3 + i] = sout[mm * 4 + c];
    }
    if (out_idx) {
        for (int i = t; i < M; i += T)
            out_idx[(size_t)b * M + i] = sout[i * 4 + 3];
    }
}

// ---------------------------------------------------------------------------
// FPS, single-wave version (round-5): thread-major mapping, split
// accumulators, single-phase DPP + ballot (min lane = min idx, exact).
// Dynamic LDS = N*3*4 + M*4*4.
// ---------------------------------------------------------------------------
template <int P>
__global__ __launch_bounds__(64) __attribute__((amdgpu_waves_per_eu(1, 1)))
void fps_wave(const float* __restrict__ xyz, int M,
              float* __restrict__ new_xyz, float* __restrict__ out_idx)
{
    constexpr int NA = (P % 4 == 0) ? 4 : 2;
    constexpr int Q = P / NA;
    const int b = blockIdx.x;
    const int lane = threadIdx.x;
    const int N = 64 * P;
    extern __shared__ float sm[];
    float* spts = sm;           // N*3
    float* sout = sm + N * 3;   // M*4
    const float* x0 = xyz + (size_t)b * N * 3;

    for (int i = lane; i < N * 3; i += 64) spts[i] = x0[i];

    float px[P], py[P], pz[P], dist[P];
#pragma unroll
    for (int j = 0; j < P; ++j) {
        int p = lane * P + j;       // thread-major
        px[j] = x0[p * 3 + 0];
        py[j] = x0[p * 3 + 1];
        pz[j] = x0[p * 3 + 2];
        dist[j] = 1e10f;
    }
    __syncthreads();

    int far = 0;
    for (int m = 0; m < M; ++m) {
        float cx = spts[far * 3 + 0];
        float cy = spts[far * 3 + 1];
        float cz = spts[far * 3 + 2];
        if (lane == 0) {
            float* so = sout + m * 4;
            so[0] = cx; so[1] = cy; so[2] = cz; so[3] = (float)far;
        }
        float bv[NA]; int bj[NA];
#pragma unroll
        for (int a = 0; a < NA; ++a) { bv[a] = -1.0f; bj[a] = 0; }
#pragma unroll
        for (int j = 0; j < Q; ++j) {
#pragma unroll
            for (int a = 0; a < NA; ++a) {
                int idx = a * Q + j;
                float dx = __fsub_rn(px[idx], cx);
                float dy = __fsub_rn(py[idx], cy);
                float dz = __fsub_rn(pz[idx], cz);
                float d  = sq3_rn(dx, dy, dz);
                float nd = fminf(dist[idx], d);
                dist[idx] = nd;
                bj[a] = (nd > bv[a]) ? idx : bj[a];
                bv[a] = fmaxf(bv[a], nd);
            }
        }
        float bvv = bv[0]; int bjj = bj[0];
#pragma unroll
        for (int a = 1; a < NA; ++a) {
            bjj = (bv[a] > bvv) ? bj[a] : bjj;
            bvv = fmaxf(bvv, bv[a]);
        }
        unsigned hi = __float_as_uint(bvv);
        unsigned h = dpp_wave_umax(hi);
        unsigned whi = (unsigned)__builtin_amdgcn_readlane((int)h, 63);
        unsigned long long mk = __ballot(hi == whi);
        int L = (int)__builtin_ctzll(mk);
        int bjL = __builtin_amdgcn_readlane(bjj, L);
        far = L * P + bjL;
    }

    __syncthreads();
    for (int i = lane; i < M * 3; i += 64) {
        int mm = i / 3, c = i - mm * 3;
        new_xyz[(size_t)b * M * 3 + i] = sout[mm * 4 + c];
    }
    if (out_idx) {
        for (int i = lane; i < M; i += 64)
            out_idx[(size_t)b * M + i] = sout[i * 4 + 3];
    }
}

// ---------------------------------------------------------------------------
// FUSED KNN + SetConv, ALL dims compile-time. 256-thread block = 4 waves =
// 4 queries. Wave ty computes the exact top-K for its query into LDS, then
// runs the setconv MLP for the same query. Same math/order as split kernels.
// LDS: int nidx[4][K]; float h[4][K*Cin3]; float h1[4][K*C1].
// ---------------------------------------------------------------------------
template <int K, int Cin, int C1, int C2>
__global__ __launch_bounds__(256)
void setconv_full(const float* __restrict__ ref_xyz, int N,
                  const float* __restrict__ ref_feat,
                  const float* __restrict__ new_xyz, int M,
                  const float* __restrict__ W0, const float* __restrict__ b0,
                  const float* __restrict__ W1, const float* __restrict__ b1,
                  float* __restrict__ out)
{
    constexpr int Cin3 = Cin + 3;
    const int b = blockIdx.y;
    const int tid = threadIdx.x;
    const int lane = tid & 63, ty = tid >> 6;
    const int m = blockIdx.x * 4 + ty;

    extern __shared__ float sm[];
    int*   nidx_s = (int*)sm;                 // [4][K]
    float* hb  = sm + 4 * K;                  // [4][K*Cin3]
    float* h1b = hb + 4 * K * Cin3;           // [4][K*C1]
    float* h  = hb  + ty * K * Cin3;
    float* h1 = h1b + ty * K * C1;

    const size_t qg = (size_t)b * M + m;
    const float* qp = new_xyz + qg * 3;
    const float qx = qp[0], qy = qp[1], qz = qp[2];

    // ---- KNN phase (exact knn_wave body) ----
    {
        const float sq = sq3_rn(qx, qy, qz);
        float dk[K]; int ik[K];
#pragma unroll
        for (int j = 0; j < K; ++j) { dk[j] = INFINITY; ik[j] = 0x7fffffff; }
        const float* rb = ref_xyz + (size_t)b * N * 3;
        for (int n = lane; n < N; n += 64) {
            const float* rp = rb + (size_t)n * 3;
            float rx = rp[0], ry = rp[1], rz = rp[2];
            float sr = sq3_rn(rx, ry, rz);
            float dot = __fadd_rn(__fadd_rn(__fmul_rn(qx, rx), __fmul_rn(qy, ry)),
                                  __fmul_rn(qz, rz));
            float d = __fadd_rn(__fsub_rn(sq, __fmul_rn(2.0f, dot)), sr);
            if (d < dk[K - 1]) {
                dk[K - 1] = d;
                ik[K - 1] = n;
#pragma unroll
                for (int j = K - 1; j > 0; --j) {
                    if (dk[j] < dk[j - 1]) {
                        float tv = dk[j]; dk[j] = dk[j - 1]; dk[j - 1] = tv;
                        int   ti = ik[j]; ik[j] = ik[j - 1]; ik[j - 1] = ti;
                    }
                }
            }
        }
        unsigned hiA[K], loA[K];
#pragma unroll
        for (int j = 0; j < K; ++j) { hiA[j] = ford(dk[j]); loA[j] = (unsigned)ik[j]; }
        int winner = 0;
        for (int r = 0; r < K; ++r) {
            unsigned bhi, blo;
            wave_argmin_u32pair(hiA[0], loA[0], bhi, blo);
            if (lane == r) winner = (int)blo;
            if (hiA[0] == bhi && loA[0] == blo) {
#pragma unroll
                for (int j = 0; j < K - 1; ++j) { hiA[j] = hiA[j + 1]; loA[j] = loA[j + 1]; }
                hiA[K - 1] = 0xFFFFFFFFu;
                loA[K - 1] = 0xFFFFFFFFu;
            }
        }
        if (lane < K) nidx_s[ty * K + lane] = winner;
    }
    __syncthreads();

    // ---- gather phase ----
    for (int j = 0; j < K; ++j) {
        int n = nidx_s[ty * K + j];
        const float* xp = ref_xyz + ((size_t)b * N + n) * 3;
        const float* fp = ref_feat + ((size_t)b * N + n) * Cin;
        for (int i = lane; i < Cin3; i += 64) {
            float v;
            if (i == 0)      v = __fsub_rn(xp[0], qx);
            else if (i == 1) v = __fsub_rn(xp[1], qy);
            else if (i == 2) v = __fsub_rn(xp[2], qz);
            else             v = fp[i - 3];
            h[j * Cin3 + i] = v;
        }
    }
    __syncthreads();

    // ---- MLP layer 1 (compile-time bounds -> acc register-resident) ----
#pragma unroll
    for (int c0 = 0; c0 < C1; c0 += 64) {
        int c = c0 + lane;
        bool act = c < C1;
        float acc[K];
        float bias = act ? b0[c] : 0.0f;
#pragma unroll
        for (int j = 0; j < K; ++j) acc[j] = bias;
        for (int i = 0; i < Cin3; ++i) {
            float w = act ? W0[i * C1 + c] : 0.0f;
#pragma unroll
            for (int j = 0; j < K; ++j) acc[j] = fmaf(h[j * Cin3 + i], w, acc[j]);
        }
        if (act) {
#pragma unroll
            for (int j = 0; j < K; ++j) h1[j * C1 + c] = fmaxf(acc[j], 0.0f);
        }
    }
    __syncthreads();

    // ---- MLP layer 2 + max-pool ----
#pragma unroll
    for (int c0 = 0; c0 < C2; c0 += 64) {
        int c = c0 + lane;
        bool act = c < C2;
        float acc[K];
        float bias = act ? b1[c] : 0.0f;
#pragma unroll
        for (int j = 0; j < K; ++j) acc[j] = bias;
        for (int i = 0; i < C1; ++i) {
            float w = act ? W1[i * C2 + c] : 0.0f;
#pragma unroll
            for (int j = 0; j < K; ++j) acc[j] = fmaf(h1[j * C1 + i], w, acc[j]);
        }
        if (act) {
            float mv = acc[0];
#pragma unroll
            for (int j = 1; j < K; ++j) mv = fmaxf(mv, acc[j]);
            out[qg * C2 + c] = fmaxf(mv, 0.0f);
        }
    }
}

// ---------------------------------------------------------------------------
// FUSED KNN + SetUpConv, ALL dims compile-time. 4 waves = 4 fine queries.
// LDS: int nidx[4][K]; float h[4][K*Cc3]; float g[4][C1+Cf].
// ---------------------------------------------------------------------------
template <int K, int Cc, int Cf, int C1, int C2>
__global__ __launch_bounds__(256)
void upconv_full(const float* __restrict__ cxyz, int Nc,
                 const float* __restrict__ cf,
                 const float* __restrict__ fxyz, int M,
                 const float* __restrict__ ff,
                 const float* __restrict__ W1, const float* __restrict__ b1,
                 const float* __restrict__ W2, const float* __restrict__ b2,
                 float* __restrict__ out)
{
    constexpr int Cc3 = Cc + 3;
    const int b = blockIdx.y;
    const int tid = threadIdx.x;
    const int lane = tid & 63, ty = tid >> 6;
    const int m = blockIdx.x * 4 + ty;

    extern __shared__ float sm[];
    int*   nidx_s = (int*)sm;                 // [4][K]
    float* hb = sm + 4 * K;                   // [4][K*Cc3]
    float* gb = hb + 4 * K * Cc3;             // [4][C1+Cf]
    float* h = hb + ty * K * Cc3;
    float* g = gb + ty * (C1 + Cf);

    const size_t qg = (size_t)b * M + m;
    const float* qp = fxyz + qg * 3;
    const float qx = qp[0], qy = qp[1], qz = qp[2];

    // ---- KNN phase ----
    {
        const float sq = sq3_rn(qx, qy, qz);
        float dk[K]; int ik[K];
#pragma unroll
        for (int j = 0; j < K; ++j) { dk[j] = INFINITY; ik[j] = 0x7fffffff; }
        const float* rb = cxyz + (size_t)b * Nc * 3;
        for (int n = lane; n < Nc; n += 64) {
            const float* rp = rb + (size_t)n * 3;
            float rx = rp[0], ry = rp[1], rz = rp[2];
            float sr = sq3_rn(rx, ry, rz);
            float dot = __fadd_rn(__fadd_rn(__fmul_rn(qx, rx), __fmul_rn(qy, ry)),
                                  __fmul_rn(qz, rz));
            float d = __fadd_rn(__fsub_rn(sq, __fmul_rn(2.0f, dot)), sr);
            if (d < dk[K - 1]) {
                dk[K - 1] = d;
                ik[K - 1] = n;
#pragma unroll
                for (int j = K - 1; j > 0; --j) {
                    if (dk[j] < dk[j - 1]) {
                        float tv = dk[j]; dk[j] = dk[j - 1]; dk[j - 1] = tv;
                        int   ti = ik[j]; ik[j] = ik[j - 1]; ik[j - 1] = ti;
                    }
                }
            }
        }
        unsigned hiA[K], loA[K];
#pragma unroll
        for (int j = 0; j < K; ++j) { hiA[j] = ford(dk[j]); loA[j] = (unsigned)ik[j]; }
        int winner = 0;
        for (int r = 0; r < K; ++r) {
            unsigned bhi, blo;
            wave_argmin_u32pair(hiA[0], loA[0], bhi, blo);
            if (lane == r) winner = (int)blo;
            if (hiA[0] == bhi && loA[0] == blo) {
#pragma unroll
                for (int j = 0; j < K - 1; ++j) { hiA[j] = hiA[j + 1]; loA[j] = loA[j + 1]; }
                hiA[K - 1] = 0xFFFFFFFFu;
                loA[K - 1] = 0xFFFFFFFFu;
            }
        }
        if (lane < K) nidx_s[ty * K + lane] = winner;
    }
    __syncthreads();

    // ---- gather phase ----
    for (int j = 0; j < K; ++j) {
        int n = nidx_s[ty * K + j];
        const float* xp = cxyz + ((size_t)b * Nc + n) * 3;
        const float* fp = cf + ((size_t)b * Nc + n) * Cc;
        for (int i = lane; i < Cc3; i += 64) {
            float v;
            if (i == 0)      v = __fsub_rn(xp[0], qx);
            else if (i == 1) v = __fsub_rn(xp[1], qy);
            else if (i == 2) v = __fsub_rn(xp[2], qz);
            else             v = fp[i - 3];
            h[j * Cc3 + i] = v;
        }
    }
    for (int i = lane; i < Cf; i += 64) g[C1 + i] = ff[qg * Cf + i];
    __syncthreads();

    // ---- MLP1 + max-pool ----
#pragma unroll
    for (int c0 = 0; c0 < C1; c0 += 64) {
        int c = c0 + lane;
        bool act = c < C1;
        float acc[K];
        float bias = act ? b1[c] : 0.0f;
#pragma unroll
        for (int j = 0; j < K; ++j) acc[j] = bias;
        for (int i = 0; i < Cc3; ++i) {
            float w = act ? W1[i * C1 + c] : 0.0f;
#pragma unroll
            for (int j = 0; j < K; ++j) acc[j] = fmaf(h[j * Cc3 + i], w, acc[j]);
        }
        if (act) {
            float mv = acc[0];
#pragma unroll
            for (int j = 1; j < K; ++j) mv = fmaxf(mv, acc[j]);
            g[c] = fmaxf(mv, 0.0f);
        }
    }
    __syncthreads();

    // ---- MLP2 on [pooled, ff] ----
    constexpr int Cg = C1 + Cf;
#pragma unroll
    for (int c0 = 0; c0 < C2; c0 += 64) {
        int c = c0 + lane;
        bool act = c < C2;
        float acc = act ? b2[c] : 0.0f;
        for (int i = 0; i < Cg; ++i) {
            float w = act ? W2[i * C2 + c] : 0.0f;
            acc = fmaf(g[i], w, acc);
        }
        if (act) out[qg * C2 + c] = fmaxf(acc, 0.0f);
    }
}

// ---------------------------------------------------------------------------
// f0 = relu(feat @ d0_W + d0_b), 3 -> 32 channels.
// ---------------------------------------------------------------------------
__global__ void f0_kernel(const float* __restrict__ feat, const float* __restrict__ W,
                          const float* __restrict__ bias, float* __restrict__ out)
{
    int t = blockIdx.x * blockDim.x + threadIdx.x;
    int n = t >> 5, c = t & 31;
    const float* f = feat + (size_t)n * 3;
    float acc = bias[c];
    acc = fmaf(f[0], W[c], acc);
    acc = fmaf(f[1], W[32 + c], acc);
    acc = fmaf(f[2], W[64 + c], acc);
    out[t] = fmaxf(acc, 0.0f);
}

// ---------------------------------------------------------------------------

extern "C" void kernel_launch(void* const* d_in, const int* in_sizes, int n_in,
                              void* d_out, int out_size, void* d_ws, size_t ws_size,
                              hipStream_t stream)
{
    const float* pc    = (const float*)d_in[0];
    const float* feat  = (const float*)d_in[1];
    const float* d0_W  = (const float*)d_in[2];
    const float* d0_b  = (const float*)d_in[3];
    const float* d1_W0 = (const float*)d_in[4];
    const float* d1_b0 = (const float*)d_in[5];
    const float* d1_W1 = (const float*)d_in[6];
    const float* d1_b1 = (const float*)d_in[7];
    const float* d2_W0 = (const float*)d_in[8];
    const float* d2_b0 = (const float*)d_in[9];
    const float* d2_W1 = (const float*)d_in[10];
    const float* d2_b1 = (const float*)d_in[11];
    const float* d3_W0 = (const float*)d_in[12];
    const float* d3_b0 = (const float*)d_in[13];
    const float* d3_W1 = (const float*)d_in[14];
    const float* d3_b1 = (const float*)d_in[15];
    const float* d4_W0 = (const float*)d_in[16];
    const float* d4_b0 = (const float*)d_in[17];
    const float* d4_W1 = (const float*)d_in[18];
    const float* d4_b1 = (const float*)d_in[19];
    const float* u4_W1 = (const float*)d_in[20];
    const float* u4_b1 = (const float*)d_in[21];
    const float* u4_W2 = (const float*)d_in[22];
    const float* u4_b2 = (const float*)d_in[23];
    const float* u3_W1 = (const float*)d_in[24];
    const float* u3_b1 = (const float*)d_in[25];
    const float* u3_W2 = (const float*)d_in[26];
    const float* u3_b2 = (const float*)d_in[27];
    const float* u2_W1 = (const float*)d_in[28];
    const float* u2_b1 = (const float*)d_in[29];
    const float* u2_W2 = (const float*)d_in[30];
    const float* u2_b2 = (const float*)d_in[31];
    const float* u1_W1 = (const float*)d_in[32];
    const float* u1_b1 = (const float*)d_in[33];
    const float* u1_W2 = (const float*)d_in[34];
    const float* u1_b2 = (const float*)d_in[35];

    float* out = (float*)d_out;
    float* o_x1 = out + 0;       // 12288
    float* o_x2 = out + 12288;   // 3072
    float* o_x3 = out + 15360;   // 768
    float* o_i1 = out + 16128;   // 4096
    float* o_i2 = out + 20224;   // 1024
    float* o_i3 = out + 21248;   // 256
    float* o_u0 = out + 21504;   // 524288
    float* o_u1 = out + 545792;  // 262144
    float* o_u2 = out + 807936;  // 131072
    float* o_u3 = out + 939008;  // 49152

    float* w = (float*)d_ws;
    float* f0 = w; w += 2 * 8192 * 32;
    float* f1 = w; w += 2 * 2048 * 64;
    float* f2 = w; w += 2 * 512 * 128;
    float* f3 = w; w += 2 * 128 * 192;
    float* f4 = w; w += 2 * 64 * 192;
    float* x4 = w; w += 2 * 64 * 3;

    const int B = 2;

    // raise dynamic-LDS caps (idempotent; gfx950 has 160KB/CU).
    static bool attr_done = false;
    if (!attr_done) {
        (void)hipFuncSetAttribute((const void*)fps_block<256, 32>,
                                  hipFuncAttributeMaxDynamicSharedMemorySize,
                                  8192 * 3 * 4 + 2048 * 4 * 4);          // 131072
        (void)hipFuncSetAttribute((const void*)setconv_full<16, 128, 128, 192>,
                                  hipFuncAttributeMaxDynamicSharedMemorySize,
                                  (4 * 16 + 4 * 16 * 131 + 4 * 16 * 128) * 4); // 66560
        (void)hipFuncSetAttribute((const void*)setconv_full<16, 192, 192, 192>,
                                  hipFuncAttributeMaxDynamicSharedMemorySize,
                                  (4 * 16 + 4 * 16 * 195 + 4 * 16 * 192) * 4); // 99328
        attr_done = true;
    }

    // f0
    f0_kernel<<<(2 * 8192 * 32) / 256, 256, 0, stream>>>(feat, d0_W, d0_b, f0);

    // ---- coordinate pyramid (FPS chain) ----
    fps_block<256, 32><<<B, 256, 8192 * 3 * 4 + 2048 * 4 * 4, stream>>>(pc, 2048, o_x1, o_i1);
    fps_block<256, 8><<<B, 256, 2048 * 3 * 4 + 512 * 4 * 4, stream>>>(o_x1, 512, o_x2, o_i2);
    fps_wave<8><<<B, 64, 512 * 3 * 4 + 128 * 4 * 4, stream>>>(o_x2, 128, o_x3, o_i3);
    fps_wave<2><<<B, 64, 128 * 3 * 4 + 64 * 4 * 4, stream>>>(o_x3, 64, x4, nullptr);

    // ---- feature pyramid down (fused knn+setconv, compile-time dims) ----
    setconv_full<16, 32, 32, 64><<<dim3(2048 / 4, B), 256,
        (4 * 16 + 4 * 16 * 35 + 4 * 16 * 32) * 4, stream>>>(
        pc, 8192, f0, o_x1, 2048, d1_W0, d1_b0, d1_W1, d1_b1, f1);
    setconv_full<16, 64, 64, 128><<<dim3(512 / 4, B), 256,
        (4 * 16 + 4 * 16 * 67 + 4 * 16 * 64) * 4, stream>>>(
        o_x1, 2048, f1, o_x2, 512, d2_W0, d2_b0, d2_W1, d2_b1, f2);
    setconv_full<16, 128, 128, 192><<<dim3(128 / 4, B), 256,
        (4 * 16 + 4 * 16 * 131 + 4 * 16 * 128) * 4, stream>>>(
        o_x2, 512, f2, o_x3, 128, d3_W0, d3_b0, d3_W1, d3_b1, f3);
    setconv_full<16, 192, 192, 192><<<dim3(64 / 4, B), 256,
        (4 * 16 + 4 * 16 * 195 + 4 * 16 * 192) * 4, stream>>>(
        o_x3, 128, f3, x4, 64, d4_W0, d4_b0, d4_W1, d4_b1, f4);

    // ---- feature pyramid up (fused knn+setupconv, compile-time dims) ----
    upconv_full<8, 192, 192, 192, 192><<<dim3(128 / 4, B), 256,
        (4 * 8 + 4 * 8 * 195 + 4 * (192 + 192)) * 4, stream>>>(
        x4, 64, f4, o_x3, 128, f3, u4_W1, u4_b1, u4_W2, u4_b2, o_u3);
    upconv_full<8, 192, 128, 128, 128><<<dim3(512 / 4, B), 256,
        (4 * 8 + 4 * 8 * 195 + 4 * (128 + 128)) * 4, stream>>>(
        o_x3, 128, o_u3, o_x2, 512, f2, u3_W1, u3_b1, u3_W2, u3_b2, o_u2);
    upconv_full<8, 128, 64, 64, 64><<<dim3(2048 / 4, B), 256,
        (4 * 8 + 4 * 8 * 131 + 4 * (64 + 64)) * 4, stream>>>(
        o_x2, 512, o_u2, o_x1, 2048, f1, u2_W1, u2_b1, u2_W2, u2_b2, o_u1);
    upconv_full<8, 64, 32, 32, 32><<<dim3(8192 / 4, B), 256,
        (4 * 8 + 4 * 8 * 67 + 4 * (32 + 32)) * 4, stream>>>(
        o_x1, 2048, o_u1, pc, 8192, f0, u1_W1, u1_b1, u1_W2, u1_b2, o_u0);
}

// Round 11
// 2788.721 us; speedup vs baseline: 1.5639x; 1.0461x over previous
//
#include <hip/hip_runtime.h>
#include <cstdint>
#include <cstddef>

// ---------------------------------------------------------------------------
// FlowNet3D-style encoder/decoder pyramid (GenFlow_unit_mask).
// Round-11: identical kernels to round-10 (2917us verified; fps1=1773,
// conv VGPR 24->56 after dim-templating). NEW: two-stream fork-join so the
// fps chain (fps2/3/4, ~250us) overlaps the conv chain (sc1/sc2/sc3), and
// f0 overlaps fps1. Events are DisableTiming; pattern is capture-safe.
// ---------------------------------------------------------------------------

static __device__ __forceinline__ float sq3_rn(float x, float y, float z) {
    // ((x*x + y*y) + z*z) strict IEEE (no fma) to bit-match numpy
    return __fadd_rn(__fadd_rn(__fmul_rn(x, x), __fmul_rn(y, y)), __fmul_rn(z, z));
}

// monotone float -> uint map (handles negatives from catastrophic cancellation)
static __device__ __forceinline__ unsigned int ford(float f) {
    unsigned int u = __float_as_uint(f);
    return u ^ ((u >> 31) ? 0xFFFFFFFFu : 0x80000000u);
}

// ---------------------------------------------------------------------------
// Branchless DPP wave-64 u32 reductions. Result lands in lane 63.
// bound_ctrl=false -> invalid-source lanes keep old value (identity).
// ---------------------------------------------------------------------------
template <int CTRL>
static __device__ __forceinline__ void dpp_umax_step(unsigned& v) {
    unsigned t = (unsigned)__builtin_amdgcn_update_dpp((int)v, (int)v, CTRL, 0xf, 0xf, false);
    v = (t > v) ? t : v;   // v_max_u32
}
template <int CTRL>
static __device__ __forceinline__ void dpp_umin_step(unsigned& v) {
    unsigned t = (unsigned)__builtin_amdgcn_update_dpp((int)v, (int)v, CTRL, 0xf, 0xf, false);
    v = (t < v) ? t : v;   // v_min_u32
}
static __device__ __forceinline__ unsigned dpp_wave_umax(unsigned v) {
    dpp_umax_step<0x111>(v);  // row_shr:1
    dpp_umax_step<0x112>(v);  // row_shr:2
    dpp_umax_step<0x114>(v);  // row_shr:4
    dpp_umax_step<0x118>(v);  // row_shr:8
    dpp_umax_step<0x142>(v);  // row_bcast:15
    dpp_umax_step<0x143>(v);  // row_bcast:31
    return v;                 // full max in lane 63
}
static __device__ __forceinline__ unsigned dpp_wave_umin(unsigned v) {
    dpp_umin_step<0x111>(v);
    dpp_umin_step<0x112>(v);
    dpp_umin_step<0x114>(v);
    dpp_umin_step<0x118>(v);
    dpp_umin_step<0x142>(v);
    dpp_umin_step<0x143>(v);
    return v;
}
static __device__ __forceinline__ void wave_argmin_u32pair(unsigned hi, unsigned lo,
                                                          unsigned& whi, unsigned& wlo) {
    unsigned h = dpp_wave_umin(hi);
    whi = (unsigned)__builtin_amdgcn_readlane((int)h, 63);
    unsigned cand = (hi == whi) ? lo : 0xFFFFFFFFu; // real lo (index) < 2^31
    unsigned l = dpp_wave_umin(cand);
    wlo = (unsigned)__builtin_amdgcn_readlane((int)l, 63);
}

// ---------------------------------------------------------------------------
// FPS, multi-wave block version (round-5 exact: ~1773us at L1).
// THREAD-MAJOR mapping: thread t owns points [t*P, (t+1)*P). Within a wave,
// smaller lane => strictly smaller point indices, so among value-ties the
// FIRST matching lane (ballot+ctz) is the exact numpy first-occurrence.
// Per-thread scan: 4 independent accumulators over contiguous quarters.
// Wave reduce = ONE 6-step DPP u32-max + readlane + ballot + readlane(bj,L).
// Cross-wave merge: max hi, min bp among matches (wave ranges disjoint).
// Zero global ops in the serial loop; ONE barrier/iter (parity slots).
// Dynamic LDS = N*3*4 (mirror) + M*4*4 (out).
// ---------------------------------------------------------------------------
template <int T, int P>
__global__ __launch_bounds__(T) __attribute__((amdgpu_waves_per_eu(1, 1)))
void fps_block(const float* __restrict__ xyz, int M,
               float* __restrict__ new_xyz, float* __restrict__ out_idx)
{
    static_assert(P % 4 == 0, "P must be a multiple of 4");
    constexpr int N = T * P;
    constexpr int NW = T / 64;
    constexpr int Q = P / 4;
    const int b = blockIdx.x;
    const int t = threadIdx.x;
    const int lane = t & 63, wave = t >> 6;

    __shared__ uint2 s_slot[2][NW];   // {hi, bp} per wave, parity-buffered
    extern __shared__ float sm[];
    float* spts = sm;           // N*3 point mirror
    float* sout = sm + N * 3;   // M*4: cx,cy,cz,(float)idx

    const float* x0 = xyz + (size_t)b * N * 3;
    for (int i = t; i < N * 3; i += T) spts[i] = x0[i];

    float px[P], py[P], pz[P], dist[P];
#pragma unroll
    for (int j = 0; j < P; ++j) {
        int p = t * P + j;          // thread-major
        px[j] = x0[p * 3 + 0];
        py[j] = x0[p * 3 + 1];
        pz[j] = x0[p * 3 + 2];
        dist[j] = 1e10f;
    }
    __syncthreads();

    int far = 0;
    for (int m = 0; m < M; ++m) {
        float cx = spts[far * 3 + 0];
        float cy = spts[far * 3 + 1];
        float cz = spts[far * 3 + 2];
        if (t == 0) {
            float* so = sout + m * 4;
            so[0] = cx; so[1] = cy; so[2] = cz; so[3] = (float)far;
        }
        float bv[4]; int bj[4];
#pragma unroll
        for (int a = 0; a < 4; ++a) { bv[a] = -1.0f; bj[a] = 0; }
#pragma unroll
        for (int j = 0; j < Q; ++j) {
#pragma unroll
            for (int a = 0; a < 4; ++a) {
                int idx = a * Q + j;
                float dx = __fsub_rn(px[idx], cx);
                float dy = __fsub_rn(py[idx], cy);
                float dz = __fsub_rn(pz[idx], cz);
                float d  = sq3_rn(dx, dy, dz);
                float nd = fminf(dist[idx], d);
                dist[idx] = nd;
                bj[a] = (nd > bv[a]) ? idx : bj[a];   // strict >: first occurrence
                bv[a] = fmaxf(bv[a], nd);
            }
        }
        float bvv = bv[0]; int bjj = bj[0];
#pragma unroll
        for (int a = 1; a < 4; ++a) {
            bjj = (bv[a] > bvv) ? bj[a] : bjj;        // tie keeps lower quarter
            bvv = fmaxf(bvv, bv[a]);
        }
        unsigned hi = __float_as_uint(bvv);           // bvv >= 0 -> monotone bits
        unsigned h = dpp_wave_umax(hi);
        unsigned whi = (unsigned)__builtin_amdgcn_readlane((int)h, 63);
        unsigned long long mk = __ballot(hi == whi);  // nonempty (max matches self)
        int L = (int)__builtin_ctzll(mk);             // min lane = min point idx
        int bjL = __builtin_amdgcn_readlane(bjj, L);
        unsigned wbp = (unsigned)((((wave << 6) + L) * P) + bjL);
        if (lane == 0) s_slot[m & 1][wave] = make_uint2(whi, wbp);
        __syncthreads();
        uint2 sv[NW];
#pragma unroll
        for (int w2 = 0; w2 < NW; ++w2) sv[w2] = s_slot[m & 1][w2];
        unsigned bhi = 0u;
#pragma unroll
        for (int w2 = 0; w2 < NW; ++w2) bhi = (sv[w2].x > bhi) ? sv[w2].x : bhi;
        unsigned blo = 0xFFFFFFFFu;
#pragma unroll
        for (int w2 = 0; w2 < NW; ++w2) {
            unsigned c = (sv[w2].x == bhi) ? sv[w2].y : 0xFFFFFFFFu;
            blo = (c < blo) ? c : blo;                // wave ranges disjoint+ordered
        }
        far = (int)blo;
    }

    // coalesced flush of accumulated outputs
    __syncthreads();
    for (int i = t; i < M * 3; i += T) {
        int mm = i / 3, c = i - mm * 3;
        new_xyz[(size_t)b * M * 3 + i] = sout[mm * 4 + c];
    }
    if (out_idx) {
        for (int i = t; i < M; i += T)
            out_idx[(size_t)b * M + i] = sout[i * 4 + 3];
    }
}

// ---------------------------------------------------------------------------
// FPS, single-wave version (round-5): thread-major mapping, split
// accumulators, single-phase DPP + ballot (min lane = min idx, exact).
// Dynamic LDS = N*3*4 + M*4*4.
// ---------------------------------------------------------------------------
template <int P>
__global__ __launch_bounds__(64) __attribute__((amdgpu_waves_per_eu(1, 1)))
void fps_wave(const float* __restrict__ xyz, int M,
              float* __restrict__ new_xyz, float* __restrict__ out_idx)
{
    constexpr int NA = (P % 4 == 0) ? 4 : 2;
    constexpr int Q = P / NA;
    const int b = blockIdx.x;
    const int lane = threadIdx.x;
    const int N = 64 * P;
    extern __shared__ float sm[];
    float* spts = sm;           // N*3
    float* sout = sm + N * 3;   // M*4
    const float* x0 = xyz + (size_t)b * N * 3;

    for (int i = lane; i < N * 3; i += 64) spts[i] = x0[i];

    float px[P], py[P], pz[P], dist[P];
#pragma unroll
    for (int j = 0; j < P; ++j) {
        int p = lane * P + j;       // thread-major
        px[j] = x0[p * 3 + 0];
        py[j] = x0[p * 3 + 1];
        pz[j] = x0[p * 3 + 2];
        dist[j] = 1e10f;
    }
    __syncthreads();

    int far = 0;
    for (int m = 0; m < M; ++m) {
        float cx = spts[far * 3 + 0];
        float cy = spts[far * 3 + 1];
        float cz = spts[far * 3 + 2];
        if (lane == 0) {
            float* so = sout + m * 4;
            so[0] = cx; so[1] = cy; so[2] = cz; so[3] = (float)far;
        }
        float bv[NA]; int bj[NA];
#pragma unroll
        for (int a = 0; a < NA; ++a) { bv[a] = -1.0f; bj[a] = 0; }
#pragma unroll
        for (int j = 0; j < Q; ++j) {
#pragma unroll
            for (int a = 0; a < NA; ++a) {
                int idx = a * Q + j;
                float dx = __fsub_rn(px[idx], cx);
                float dy = __fsub_rn(py[idx], cy);
                float dz = __fsub_rn(pz[idx], cz);
                float d  = sq3_rn(dx, dy, dz);
                float nd = fminf(dist[idx], d);
                dist[idx] = nd;
                bj[a] = (nd > bv[a]) ? idx : bj[a];
                bv[a] = fmaxf(bv[a], nd);
            }
        }
        float bvv = bv[0]; int bjj = bj[0];
#pragma unroll
        for (int a = 1; a < NA; ++a) {
            bjj = (bv[a] > bvv) ? bj[a] : bjj;
            bvv = fmaxf(bvv, bv[a]);
        }
        unsigned hi = __float_as_uint(bvv);
        unsigned h = dpp_wave_umax(hi);
        unsigned whi = (unsigned)__builtin_amdgcn_readlane((int)h, 63);
        unsigned long long mk = __ballot(hi == whi);
        int L = (int)__builtin_ctzll(mk);
        int bjL = __builtin_amdgcn_readlane(bjj, L);
        far = L * P + bjL;
    }

    __syncthreads();
    for (int i = lane; i < M * 3; i += 64) {
        int mm = i / 3, c = i - mm * 3;
        new_xyz[(size_t)b * M * 3 + i] = sout[mm * 4 + c];
    }
    if (out_idx) {
        for (int i = lane; i < M; i += 64)
            out_idx[(size_t)b * M + i] = sout[i * 4 + 3];
    }
}

// ---------------------------------------------------------------------------
// FUSED KNN + SetConv, ALL dims compile-time. 256-thread block = 4 waves =
// 4 queries. Wave ty computes the exact top-K for its query into LDS, then
// runs the setconv MLP for the same query. Same math/order as split kernels.
// LDS: int nidx[4][K]; float h[4][K*Cin3]; float h1[4][K*C1].
// ---------------------------------------------------------------------------
template <int K, int Cin, int C1, int C2>
__global__ __launch_bounds__(256)
void setconv_full(const float* __restrict__ ref_xyz, int N,
                  const float* __restrict__ ref_feat,
                  const float* __restrict__ new_xyz, int M,
                  const float* __restrict__ W0, const float* __restrict__ b0,
                  const float* __restrict__ W1, const float* __restrict__ b1,
                  float* __restrict__ out)
{
    constexpr int Cin3 = Cin + 3;
    const int b = blockIdx.y;
    const int tid = threadIdx.x;
    const int lane = tid & 63, ty = tid >> 6;
    const int m = blockIdx.x * 4 + ty;

    extern __shared__ float sm[];
    int*   nidx_s = (int*)sm;                 // [4][K]
    float* hb  = sm + 4 * K;                  // [4][K*Cin3]
    float* h1b = hb + 4 * K * Cin3;           // [4][K*C1]
    float* h  = hb  + ty * K * Cin3;
    float* h1 = h1b + ty * K * C1;

    const size_t qg = (size_t)b * M + m;
    const float* qp = new_xyz + qg * 3;
    const float qx = qp[0], qy = qp[1], qz = qp[2];

    // ---- KNN phase (exact knn_wave body) ----
    {
        const float sq = sq3_rn(qx, qy, qz);
        float dk[K]; int ik[K];
#pragma unroll
        for (int j = 0; j < K; ++j) { dk[j] = INFINITY; ik[j] = 0x7fffffff; }
        const float* rb = ref_xyz + (size_t)b * N * 3;
        for (int n = lane; n < N; n += 64) {
            const float* rp = rb + (size_t)n * 3;
            float rx = rp[0], ry = rp[1], rz = rp[2];
            float sr = sq3_rn(rx, ry, rz);
            float dot = __fadd_rn(__fadd_rn(__fmul_rn(qx, rx), __fmul_rn(qy, ry)),
                                  __fmul_rn(qz, rz));
            float d = __fadd_rn(__fsub_rn(sq, __fmul_rn(2.0f, dot)), sr);
            if (d < dk[K - 1]) {
                dk[K - 1] = d;
                ik[K - 1] = n;
#pragma unroll
                for (int j = K - 1; j > 0; --j) {
                    if (dk[j] < dk[j - 1]) {
                        float tv = dk[j]; dk[j] = dk[j - 1]; dk[j - 1] = tv;
                        int   ti = ik[j]; ik[j] = ik[j - 1]; ik[j - 1] = ti;
                    }
                }
            }
        }
        unsigned hiA[K], loA[K];
#pragma unroll
        for (int j = 0; j < K; ++j) { hiA[j] = ford(dk[j]); loA[j] = (unsigned)ik[j]; }
        int winner = 0;
        for (int r = 0; r < K; ++r) {
            unsigned bhi, blo;
            wave_argmin_u32pair(hiA[0], loA[0], bhi, blo);
            if (lane == r) winner = (int)blo;
            if (hiA[0] == bhi && loA[0] == blo) {
#pragma unroll
                for (int j = 0; j < K - 1; ++j) { hiA[j] = hiA[j + 1]; loA[j] = loA[j + 1]; }
                hiA[K - 1] = 0xFFFFFFFFu;
                loA[K - 1] = 0xFFFFFFFFu;
            }
        }
        if (lane < K) nidx_s[ty * K + lane] = winner;
    }
    __syncthreads();

    // ---- gather phase ----
    for (int j = 0; j < K; ++j) {
        int n = nidx_s[ty * K + j];
        const float* xp = ref_xyz + ((size_t)b * N + n) * 3;
        const float* fp = ref_feat + ((size_t)b * N + n) * Cin;
        for (int i = lane; i < Cin3; i += 64) {
            float v;
            if (i == 0)      v = __fsub_rn(xp[0], qx);
            else if (i == 1) v = __fsub_rn(xp[1], qy);
            else if (i == 2) v = __fsub_rn(xp[2], qz);
            else             v = fp[i - 3];
            h[j * Cin3 + i] = v;
        }
    }
    __syncthreads();

    // ---- MLP layer 1 (compile-time bounds -> acc register-resident) ----
#pragma unroll
    for (int c0 = 0; c0 < C1; c0 += 64) {
        int c = c0 + lane;
        bool act = c < C1;
        float acc[K];
        float bias = act ? b0[c] : 0.0f;
#pragma unroll
        for (int j = 0; j < K; ++j) acc[j] = bias;
        for (int i = 0; i < Cin3; ++i) {
            float w = act ? W0[i * C1 + c] : 0.0f;
#pragma unroll
            for (int j = 0; j < K; ++j) acc[j] = fmaf(h[j * Cin3 + i], w, acc[j]);
        }
        if (act) {
#pragma unroll
            for (int j = 0; j < K; ++j) h1[j * C1 + c] = fmaxf(acc[j], 0.0f);
        }
    }
    __syncthreads();

    // ---- MLP layer 2 + max-pool ----
#pragma unroll
    for (int c0 = 0; c0 < C2; c0 += 64) {
        int c = c0 + lane;
        bool act = c < C2;
        float acc[K];
        float bias = act ? b1[c] : 0.0f;
#pragma unroll
        for (int j = 0; j < K; ++j) acc[j] = bias;
        for (int i = 0; i < C1; ++i) {
            float w = act ? W1[i * C2 + c] : 0.0f;
#pragma unroll
            for (int j = 0; j < K; ++j) acc[j] = fmaf(h1[j * C1 + i], w, acc[j]);
        }
        if (act) {
            float mv = acc[0];
#pragma unroll
            for (int j = 1; j < K; ++j) mv = fmaxf(mv, acc[j]);
            out[qg * C2 + c] = fmaxf(mv, 0.0f);
        }
    }
}

// ---------------------------------------------------------------------------
// FUSED KNN + SetUpConv, ALL dims compile-time. 4 waves = 4 fine queries.
// LDS: int nidx[4][K]; float h[4][K*Cc3]; float g[4][C1+Cf].
// ---------------------------------------------------------------------------
template <int K, int Cc, int Cf, int C1, int C2>
__global__ __launch_bounds__(256)
void upconv_full(const float* __restrict__ cxyz, int Nc,
                 const float* __restrict__ cf,
                 const float* __restrict__ fxyz, int M,
                 const float* __restrict__ ff,
                 const float* __restrict__ W1, const float* __restrict__ b1,
                 const float* __restrict__ W2, const float* __restrict__ b2,
                 float* __restrict__ out)
{
    constexpr int Cc3 = Cc + 3;
    const int b = blockIdx.y;
    const int tid = threadIdx.x;
    const int lane = tid & 63, ty = tid >> 6;
    const int m = blockIdx.x * 4 + ty;

    extern __shared__ float sm[];
    int*   nidx_s = (int*)sm;                 // [4][K]
    float* hb = sm + 4 * K;                   // [4][K*Cc3]
    float* gb = hb + 4 * K * Cc3;             // [4][C1+Cf]
    float* h = hb + ty * K * Cc3;
    float* g = gb + ty * (C1 + Cf);

    const size_t qg = (size_t)b * M + m;
    const float* qp = fxyz + qg * 3;
    const float qx = qp[0], qy = qp[1], qz = qp[2];

    // ---- KNN phase ----
    {
        const float sq = sq3_rn(qx, qy, qz);
        float dk[K]; int ik[K];
#pragma unroll
        for (int j = 0; j < K; ++j) { dk[j] = INFINITY; ik[j] = 0x7fffffff; }
        const float* rb = cxyz + (size_t)b * Nc * 3;
        for (int n = lane; n < Nc; n += 64) {
            const float* rp = rb + (size_t)n * 3;
            float rx = rp[0], ry = rp[1], rz = rp[2];
            float sr = sq3_rn(rx, ry, rz);
            float dot = __fadd_rn(__fadd_rn(__fmul_rn(qx, rx), __fmul_rn(qy, ry)),
                                  __fmul_rn(qz, rz));
            float d = __fadd_rn(__fsub_rn(sq, __fmul_rn(2.0f, dot)), sr);
            if (d < dk[K - 1]) {
                dk[K - 1] = d;
                ik[K - 1] = n;
#pragma unroll
                for (int j = K - 1; j > 0; --j) {
                    if (dk[j] < dk[j - 1]) {
                        float tv = dk[j]; dk[j] = dk[j - 1]; dk[j - 1] = tv;
                        int   ti = ik[j]; ik[j] = ik[j - 1]; ik[j - 1] = ti;
                    }
                }
            }
        }
        unsigned hiA[K], loA[K];
#pragma unroll
        for (int j = 0; j < K; ++j) { hiA[j] = ford(dk[j]); loA[j] = (unsigned)ik[j]; }
        int winner = 0;
        for (int r = 0; r < K; ++r) {
            unsigned bhi, blo;
            wave_argmin_u32pair(hiA[0], loA[0], bhi, blo);
            if (lane == r) winner = (int)blo;
            if (hiA[0] == bhi && loA[0] == blo) {
#pragma unroll
                for (int j = 0; j < K - 1; ++j) { hiA[j] = hiA[j + 1]; loA[j] = loA[j + 1]; }
                hiA[K - 1] = 0xFFFFFFFFu;
                loA[K - 1] = 0xFFFFFFFFu;
            }
        }
        if (lane < K) nidx_s[ty * K + lane] = winner;
    }
    __syncthreads();

    // ---- gather phase ----
    for (int j = 0; j < K; ++j) {
        int n = nidx_s[ty * K + j];
        const float* xp = cxyz + ((size_t)b * Nc + n) * 3;
        const float* fp = cf + ((size_t)b * Nc + n) * Cc;
        for (int i = lane; i < Cc3; i += 64) {
            float v;
            if (i == 0)      v = __fsub_rn(xp[0], qx);
            else if (i == 1) v = __fsub_rn(xp[1], qy);
            else if (i == 2) v = __fsub_rn(xp[2], qz);
            else             v = fp[i - 3];
            h[j * Cc3 + i] = v;
        }
    }
    for (int i = lane; i < Cf; i += 64) g[C1 + i] = ff[qg * Cf + i];
    __syncthreads();

    // ---- MLP1 + max-pool ----
#pragma unroll
    for (int c0 = 0; c0 < C1; c0 += 64) {
        int c = c0 + lane;
        bool act = c < C1;
        float acc[K];
        float bias = act ? b1[c] : 0.0f;
#pragma unroll
        for (int j = 0; j < K; ++j) acc[j] = bias;
        for (int i = 0; i < Cc3; ++i) {
            float w = act ? W1[i * C1 + c] : 0.0f;
#pragma unroll
            for (int j = 0; j < K; ++j) acc[j] = fmaf(h[j * Cc3 + i], w, acc[j]);
        }
        if (act) {
            float mv = acc[0];
#pragma unroll
            for (int j = 1; j < K; ++j) mv = fmaxf(mv, acc[j]);
            g[c] = fmaxf(mv, 0.0f);
        }
    }
    __syncthreads();

    // ---- MLP2 on [pooled, ff] ----
    constexpr int Cg = C1 + Cf;
#pragma unroll
    for (int c0 = 0; c0 < C2; c0 += 64) {
        int c = c0 + lane;
        bool act = c < C2;
        float acc = act ? b2[c] : 0.0f;
        for (int i = 0; i < Cg; ++i) {
            float w = act ? W2[i * C2 + c] : 0.0f;
            acc = fmaf(g[i], w, acc);
        }
        if (act) out[qg * C2 + c] = fmaxf(acc, 0.0f);
    }
}

// ---------------------------------------------------------------------------
// f0 = relu(feat @ d0_W + d0_b), 3 -> 32 channels.
// ---------------------------------------------------------------------------
__global__ void f0_kernel(const float* __restrict__ feat, const float* __restrict__ W,
                          const float* __restrict__ bias, float* __restrict__ out)
{
    int t = blockIdx.x * blockDim.x + threadIdx.x;
    int n = t >> 5, c = t & 31;
    const float* f = feat + (size_t)n * 3;
    float acc = bias[c];
    acc = fmaf(f[0], W[c], acc);
    acc = fmaf(f[1], W[32 + c], acc);
    acc = fmaf(f[2], W[64 + c], acc);
    out[t] = fmaxf(acc, 0.0f);
}

// ---------------------------------------------------------------------------

extern "C" void kernel_launch(void* const* d_in, const int* in_sizes, int n_in,
                              void* d_out, int out_size, void* d_ws, size_t ws_size,
                              hipStream_t stream)
{
    const float* pc    = (const float*)d_in[0];
    const float* feat  = (const float*)d_in[1];
    const float* d0_W  = (const float*)d_in[2];
    const float* d0_b  = (const float*)d_in[3];
    const float* d1_W0 = (const float*)d_in[4];
    const float* d1_b0 = (const float*)d_in[5];
    const float* d1_W1 = (const float*)d_in[6];
    const float* d1_b1 = (const float*)d_in[7];
    const float* d2_W0 = (const float*)d_in[8];
    const float* d2_b0 = (const float*)d_in[9];
    const float* d2_W1 = (const float*)d_in[10];
    const float* d2_b1 = (const float*)d_in[11];
    const float* d3_W0 = (const float*)d_in[12];
    const float* d3_b0 = (const float*)d_in[13];
    const float* d3_W1 = (const float*)d_in[14];
    const float* d3_b1 = (const float*)d_in[15];
    const float* d4_W0 = (const float*)d_in[16];
    const float* d4_b0 = (const float*)d_in[17];
    const float* d4_W1 = (const float*)d_in[18];
    const float* d4_b1 = (const float*)d_in[19];
    const float* u4_W1 = (const float*)d_in[20];
    const float* u4_b1 = (const float*)d_in[21];
    const float* u4_W2 = (const float*)d_in[22];
    const float* u4_b2 = (const float*)d_in[23];
    const float* u3_W1 = (const float*)d_in[24];
    const float* u3_b1 = (const float*)d_in[25];
    const float* u3_W2 = (const float*)d_in[26];
    const float* u3_b2 = (const float*)d_in[27];
    const float* u2_W1 = (const float*)d_in[28];
    const float* u2_b1 = (const float*)d_in[29];
    const float* u2_W2 = (const float*)d_in[30];
    const float* u2_b2 = (const float*)d_in[31];
    const float* u1_W1 = (const float*)d_in[32];
    const float* u1_b1 = (const float*)d_in[33];
    const float* u1_W2 = (const float*)d_in[34];
    const float* u1_b2 = (const float*)d_in[35];

    float* out = (float*)d_out;
    float* o_x1 = out + 0;       // 12288
    float* o_x2 = out + 12288;   // 3072
    float* o_x3 = out + 15360;   // 768
    float* o_i1 = out + 16128;   // 4096
    float* o_i2 = out + 20224;   // 1024
    float* o_i3 = out + 21248;   // 256
    float* o_u0 = out + 21504;   // 524288
    float* o_u1 = out + 545792;  // 262144
    float* o_u2 = out + 807936;  // 131072
    float* o_u3 = out + 939008;  // 49152

    float* w = (float*)d_ws;
    float* f0 = w; w += 2 * 8192 * 32;
    float* f1 = w; w += 2 * 2048 * 64;
    float* f2 = w; w += 2 * 512 * 128;
    float* f3 = w; w += 2 * 128 * 192;
    float* f4 = w; w += 2 * 64 * 192;
    float* x4 = w; w += 2 * 64 * 3;

    const int B = 2;

    // one-time setup: LDS caps + second stream + fork/join events
    // (stream/event creation are not stream ops -> legal under capture;
    //  events are DisableTiming as required for capture dependencies)
    static bool init_done = false;
    static hipStream_t s2 = nullptr;
    static hipEvent_t evFork = nullptr, evX1 = nullptr, evX2 = nullptr,
                      evX3 = nullptr, evX4 = nullptr, evJoin = nullptr;
    if (!init_done) {
        (void)hipFuncSetAttribute((const void*)fps_block<256, 32>,
                                  hipFuncAttributeMaxDynamicSharedMemorySize,
                                  8192 * 3 * 4 + 2048 * 4 * 4);          // 131072
        (void)hipFuncSetAttribute((const void*)setconv_full<16, 128, 128, 192>,
                                  hipFuncAttributeMaxDynamicSharedMemorySize,
                                  (4 * 16 + 4 * 16 * 131 + 4 * 16 * 128) * 4); // 66560
        (void)hipFuncSetAttribute((const void*)setconv_full<16, 192, 192, 192>,
                                  hipFuncAttributeMaxDynamicSharedMemorySize,
                                  (4 * 16 + 4 * 16 * 195 + 4 * 16 * 192) * 4); // 99328
        (void)hipStreamCreateWithFlags(&s2, hipStreamNonBlocking);
        (void)hipEventCreateWithFlags(&evFork, hipEventDisableTiming);
        (void)hipEventCreateWithFlags(&evX1, hipEventDisableTiming);
        (void)hipEventCreateWithFlags(&evX2, hipEventDisableTiming);
        (void)hipEventCreateWithFlags(&evX3, hipEventDisableTiming);
        (void)hipEventCreateWithFlags(&evX4, hipEventDisableTiming);
        (void)hipEventCreateWithFlags(&evJoin, hipEventDisableTiming);
        init_done = true;
    }

    // ---- fork: s2 branches off the main stream ----
    (void)hipEventRecord(evFork, stream);
    (void)hipStreamWaitEvent(s2, evFork, 0);

    // f0 on s2, concurrent with fps1
    f0_kernel<<<(2 * 8192 * 32) / 256, 256, 0, s2>>>(feat, d0_W, d0_b, f0);

    // ---- fps chain on main stream ----
    fps_block<256, 32><<<B, 256, 8192 * 3 * 4 + 2048 * 4 * 4, stream>>>(pc, 2048, o_x1, o_i1);
    (void)hipEventRecord(evX1, stream);
    fps_block<256, 8><<<B, 256, 2048 * 3 * 4 + 512 * 4 * 4, stream>>>(o_x1, 512, o_x2, o_i2);
    (void)hipEventRecord(evX2, stream);
    fps_wave<8><<<B, 64, 512 * 3 * 4 + 128 * 4 * 4, stream>>>(o_x2, 128, o_x3, o_i3);
    (void)hipEventRecord(evX3, stream);
    fps_wave<2><<<B, 64, 128 * 3 * 4 + 64 * 4 * 4, stream>>>(o_x3, 64, x4, nullptr);
    (void)hipEventRecord(evX4, stream);

    // ---- feature chain on s2, gated on the fps outputs it needs ----
    (void)hipStreamWaitEvent(s2, evX1, 0);   // o_x1 ready
    setconv_full<16, 32, 32, 64><<<dim3(2048 / 4, B), 256,
        (4 * 16 + 4 * 16 * 35 + 4 * 16 * 32) * 4, s2>>>(
        pc, 8192, f0, o_x1, 2048, d1_W0, d1_b0, d1_W1, d1_b1, f1);
    (void)hipStreamWaitEvent(s2, evX2, 0);   // o_x2 ready
    setconv_full<16, 64, 64, 128><<<dim3(512 / 4, B), 256,
        (4 * 16 + 4 * 16 * 67 + 4 * 16 * 64) * 4, s2>>>(
        o_x1, 2048, f1, o_x2, 512, d2_W0, d2_b0, d2_W1, d2_b1, f2);
    (void)hipStreamWaitEvent(s2, evX3, 0);   // o_x3 ready
    setconv_full<16, 128, 128, 192><<<dim3(128 / 4, B), 256,
        (4 * 16 + 4 * 16 * 131 + 4 * 16 * 128) * 4, s2>>>(
        o_x2, 512, f2, o_x3, 128, d3_W0, d3_b0, d3_W1, d3_b1, f3);
    (void)hipStreamWaitEvent(s2, evX4, 0);   // x4 ready
    setconv_full<16, 192, 192, 192><<<dim3(64 / 4, B), 256,
        (4 * 16 + 4 * 16 * 195 + 4 * 16 * 192) * 4, s2>>>(
        o_x3, 128, f3, x4, 64, d4_W0, d4_b0, d4_W1, d4_b1, f4);

    upconv_full<8, 192, 192, 192, 192><<<dim3(128 / 4, B), 256,
        (4 * 8 + 4 * 8 * 195 + 4 * (192 + 192)) * 4, s2>>>(
        x4, 64, f4, o_x3, 128, f3, u4_W1, u4_b1, u4_W2, u4_b2, o_u3);
    upconv_full<8, 192, 128, 128, 128><<<dim3(512 / 4, B), 256,
        (4 * 8 + 4 * 8 * 195 + 4 * (128 + 128)) * 4, s2>>>(
        o_x3, 128, o_u3, o_x2, 512, f2, u3_W1, u3_b1, u3_W2, u3_b2, o_u2);
    upconv_full<8, 128, 64, 64, 64><<<dim3(2048 / 4, B), 256,
        (4 * 8 + 4 * 8 * 131 + 4 * (64 + 64)) * 4, s2>>>(
        o_x2, 512, o_u2, o_x1, 2048, f1, u2_W1, u2_b1, u2_W2, u2_b2, o_u1);
    upconv_full<8, 64, 32, 32, 32><<<dim3(8192 / 4, B), 256,
        (4 * 8 + 4 * 8 * 67 + 4 * (32 + 32)) * 4, s2>>>(
        o_x1, 2048, o_u1, pc, 8192, f0, u1_W1, u1_b1, u1_W2, u1_b2, o_u0);

    // ---- join: main stream waits for the feature chain ----
    (void)hipEventRecord(evJoin, s2);
    (void)hipStreamWaitEvent(stream, evJoin, 0);
}